// Round 9
// baseline (153.401 us; speedup 1.0000x reference)
//
#include <hip/hip_runtime.h>
#include <hip/hip_bf16.h>
#include <math.h>

// Problem constants
#define BATCH 2
#define SEQ   2048
#define DIM   1024
#define HEADS 16
#define DH    64
#define MROWS (BATCH*SEQ)      // 4096
#define NTOT  3072             // gemm output cols: q(1024) | k(1024) | v(1024)
#define KDIM  1024

typedef float f32x4 __attribute__((ext_vector_type(4)));
typedef __bf16 bf16x8 __attribute__((ext_vector_type(8)));
typedef __bf16 bf16x4 __attribute__((ext_vector_type(4)));
typedef __bf16 bf16x2 __attribute__((ext_vector_type(2)));

// Fragment-order buffers (1KB block = 64 lanes x 16B chunk, lane ln = featquad*16 + (token&15)):
//  qF/kF: block index ((b*128 + g)*16 + h)*2 + kf      g = token-group (16 tokens)
//  vF   : block index ((bh*32 + kvt)*4 + nb)*2 + kf    kvt = kv/64, dv-group nb
// One 1KB block == one wave64 global_load_lds (base + ln*16B) == one b128 LDS frag read.

__device__ __forceinline__ void gload_lds16(const void* g, void* l) {
    __builtin_amdgcn_global_load_lds((__attribute__((address_space(1))) void*)g,
                                     (__attribute__((address_space(3))) void*)l,
                                     16, 0, 0);
}

// raw v_exp_f32: skips OCML exp2f's denormal-fixup sequence. Validated v15/v16/v17b.
__device__ __forceinline__ float fast_exp2(float x) {
    float r;
    asm("v_exp_f32 %0, %1" : "=v"(r) : "v"(x));
    return r;
}

// ---------------------------------------------- prep: cast x -> bf16  +  transpose W -> Wt
__global__ void prep_kernel(const float* __restrict__ x,
                            const float* __restrict__ Wqk, const float* __restrict__ Wv,
                            __bf16* __restrict__ xb, __bf16* __restrict__ Wt) {
    __shared__ float T[64*65];
    const int bx = blockIdx.x;
    const int tid = threadIdx.x;
    if (bx < 4096) {
        int i = bx * 256 + tid;                   // 1M float4 = 4M floats exactly
        float4 f = ((const float4*)x)[i];
        bf16x4 o;
        o.x = (__bf16)f.x; o.y = (__bf16)f.y; o.z = (__bf16)f.z; o.w = (__bf16)f.w;
        ((bf16x4*)xb)[i] = o;
    } else {
        const int t = bx - 4096;                  // 0..767
        const int n0 = (t % 48) * 64;
        const int k0 = (t / 48) * 64;
#pragma unroll
        for (int i = 0; i < 16; ++i) {
            int idx = i*256 + tid;
            int kk = idx >> 6, nn = idx & 63;
            int n = n0 + nn;
            float v = (n < 2048) ? Wqk[(size_t)(k0+kk)*2048 + n]
                                 : Wv [(size_t)(k0+kk)*1024 + (n - 2048)];
            T[kk*65 + nn] = v;
        }
        __syncthreads();
#pragma unroll
        for (int i = 0; i < 16; ++i) {
            int idx = i*256 + tid;
            int nn = idx >> 6, kk = idx & 63;
            Wt[(size_t)(n0+nn)*KDIM + k0 + kk] = (__bf16)T[kk*65 + nn];
        }
    }
}

// ---------------------------------------------------------------- GEMM v6 (r11, unchanged)
#define BM 128
#define BN 128
#define BK 64

__global__ __launch_bounds__(256) void gemm_qkv_kernel(const __bf16* __restrict__ A,
                                                       const __bf16* __restrict__ Bt,
                                                       const float* __restrict__ bqk,
                                                       const float* __restrict__ bv,
                                                       __bf16* __restrict__ qF,
                                                       __bf16* __restrict__ kF,
                                                       __bf16* __restrict__ vF) {
    __shared__ alignas(16) __bf16 As[BM*BK];
    __shared__ alignas(16) __bf16 Bs[BN*BK];
    const int tid = threadIdx.x;
    const int wv = tid >> 6, ln = tid & 63;
    const int quad = ln >> 4, lm = ln & 15;
    const int m0 = blockIdx.y * BM, n0 = blockIdx.x * BN;
    const int wm = (wv >> 1) * 64, wn = (wv & 1) * 64;
    const int sw = lm & 7;

    f32x4 acc[4][4] = {};

    if (n0 < 2048) {
        // ---------------- q/k path: acc[nt][mt] = C^T tiles ----------------
        for (int kt = 0; kt < KDIM/BK; ++kt) {
            const int k0 = kt * BK;
            __syncthreads();
#pragma unroll
            for (int i = 0; i < 4; ++i) {
                int slot = wv*256 + i*64 + ln;
                int row = slot >> 3, p = slot & 7;
                int cc = (p ^ (row & 7)) * 8;
                gload_lds16(A  + (size_t)(m0 + row)*KDIM + k0 + cc, &As[(wv*256 + i*64)*8]);
                gload_lds16(Bt + (size_t)(n0 + row)*KDIM + k0 + cc, &Bs[(wv*256 + i*64)*8]);
            }
            __syncthreads();
#pragma unroll
            for (int kf = 0; kf < 2; ++kf) {
                bf16x8 af[4], bfr[4];
#pragma unroll
                for (int mt = 0; mt < 4; ++mt)
                    af[mt] = *(const bf16x8*)&As[(wm + mt*16 + lm)*BK + (((kf<<2)|quad) ^ sw)*8];
#pragma unroll
                for (int nt = 0; nt < 4; ++nt)
                    bfr[nt] = *(const bf16x8*)&Bs[(wn + nt*16 + lm)*BK + (((kf<<2)|quad) ^ sw)*8];
#pragma unroll
                for (int nt = 0; nt < 4; ++nt)
#pragma unroll
                    for (int mt = 0; mt < 4; ++mt)
                        acc[nt][mt] = __builtin_amdgcn_mfma_f32_16x16x32_bf16(bfr[nt], af[mt], acc[nt][mt], 0, 0, 0);
            }
        }
        __bf16* dst = (n0 < 1024) ? qF : kF;        // block-uniform
#pragma unroll
        for (int nt = 0; nt < 4; ++nt) {
            int f = n0 + wn + nt*16 + quad*4;
            float4 bs4 = *(const float4*)&bqk[f];
            int fl = f & 1023;
            int h  = fl >> 6;
            int ff = fl & 63;
            int fquad = (ff >> 3) & 3;
            int j0 = ff & 7;
            int kf = ff >> 5;
#pragma unroll
            for (int mt = 0; mt < 4; ++mt) {
                int m = m0 + wm + mt*16 + lm;
                int b = m >> 11, g = (m & 2047) >> 4;
                bf16x4 pk;
                pk[0] = (__bf16)(acc[nt][mt][0] + bs4.x);
                pk[1] = (__bf16)(acc[nt][mt][1] + bs4.y);
                pk[2] = (__bf16)(acc[nt][mt][2] + bs4.z);
                pk[3] = (__bf16)(acc[nt][mt][3] + bs4.w);
                size_t blk = (((size_t)(b*128 + g)*16 + h)*2 + kf);
                *(bf16x4*)&dst[blk*512 + (fquad*16 + lm)*8 + j0] = pk;
            }
        }
    } else {
        // ---------------- v path: acc[mt][nt] = C tiles -> vF frag-order ----------------
        for (int kt = 0; kt < KDIM/BK; ++kt) {
            const int k0 = kt * BK;
            __syncthreads();
#pragma unroll
            for (int i = 0; i < 4; ++i) {
                int slot = wv*256 + i*64 + ln;
                int row = slot >> 3, p = slot & 7;
                int cc = (p ^ (row & 7)) * 8;
                gload_lds16(A  + (size_t)(m0 + row)*KDIM + k0 + cc, &As[(wv*256 + i*64)*8]);
                gload_lds16(Bt + (size_t)(n0 + row)*KDIM + k0 + cc, &Bs[(wv*256 + i*64)*8]);
            }
            __syncthreads();
#pragma unroll
            for (int kf = 0; kf < 2; ++kf) {
                bf16x8 af[4], bfr[4];
#pragma unroll
                for (int mt = 0; mt < 4; ++mt)
                    af[mt] = *(const bf16x8*)&As[(wm + mt*16 + lm)*BK + (((kf<<2)|quad) ^ sw)*8];
#pragma unroll
                for (int nt = 0; nt < 4; ++nt)
                    bfr[nt] = *(const bf16x8*)&Bs[(wn + nt*16 + lm)*BK + (((kf<<2)|quad) ^ sw)*8];
#pragma unroll
                for (int mt = 0; mt < 4; ++mt)
#pragma unroll
                    for (int nt = 0; nt < 4; ++nt)
                        acc[mt][nt] = __builtin_amdgcn_mfma_f32_16x16x32_bf16(af[mt], bfr[nt], acc[mt][nt], 0, 0, 0);
            }
        }
#pragma unroll
        for (int mt = 0; mt < 4; ++mt) {
            int s4 = m0 + wm + mt*16 + quad*4;
            int b   = s4 >> 11;
            int kvt = (s4 & 2047) >> 6;
            int kv  = s4 & 63;
            int kf  = kv >> 5;
            int qv  = (kv >> 3) & 3;
            int j0  = kv & 7;
#pragma unroll
            for (int nt = 0; nt < 4; ++nt) {
                int cv = n0 + wn + nt*16 + lm - 2048;
                int h = cv >> 6, dv = cv & 63, nb = dv >> 4;
                float bs = bv[cv];
                bf16x4 pk;
#pragma unroll
                for (int r = 0; r < 4; ++r) pk[r] = (__bf16)(acc[mt][nt][r] + bs);
                size_t blk = (((size_t)((b*16 + h)*32 + kvt)*4 + nb)*2 + kf);
                *(bf16x4*)&vF[blk*512 + (qv*16 + lm)*8 + j0] = pk;
            }
        }
    }
}

// ---------------------------------------------------------------- flash attention v19
// v18 (142.8us) + KV-SPLIT WAVE SPECIALIZATION. v18 accounting: every wave read the FULL
// 32KB K+V tile per step for 16 q-rows -> 256KB LDS reads/block-step -> ~21us pure
// ds_read_b128 floor (85 B/cyc/CU) = the dominant attn cost. Because softmax here is
// max-free (P = exp2(S)), l and O are pure kv-sums -> kv partitions across waves:
//   8 waves = 4 q-groups (32 rows) x 2 kv-halves (64 kv). Each wave reads HALF the
//   K/V tile (16 b128/step) for 2x q-rows -> total LDS reads/block-step halve (128KB).
// Same grid/occupancy/staging/balance as v18 (anti-v15). Final combine: kv-half-1 waves
// write partial O (32KB, aliased on Ks) + l (2KB, on Vs) once per block; half-0 waves
// add + write out. kv sum order changes (half0+half1 in f32) -> absmax may move slightly;
// threshold 0.0456 has 3x headroom. Fully-masked final-step wave-tiles skip uniformly.
// One-tile PV pipeline, permlane P-redistribution, KVBLK=128, fast_exp2 all retained.

__global__ __launch_bounds__(512, 4) void attn_kernel(const __bf16* __restrict__ qF,
                                                      const __bf16* __restrict__ kF,
                                                      const __bf16* __restrict__ vF,
                                                      float* __restrict__ out) {
    const int bh = blockIdx.x;
    const int b = bh >> 4, h = bh & 15;
    const int tyr = blockIdx.y;                     // 0..15
    const int ty = (tyr < 8) ? (15 - tyr) : (tyr - 8);  // heavy-first + pairwise balanced
    const int qb = ty * 128;
    const int tid = threadIdx.x, wv = tid >> 6, ln = tid & 63;
    const int quad = ln >> 4, lm = ln & 15;
    const int qg2 = wv & 3;                         // q-group: 32 rows
    const int h1  = wv >> 2;                        // kv-half: 64 kv
    const int q0w = qb + qg2*32;                    // this wave's 32 q-rows (two 16-row frags)

    __shared__ alignas(16) __bf16 Ks[2][16*512];    // 32KB: [buf][slot nt*2+kf][frag]
    __shared__ alignas(16) __bf16 Vs[2][16*512];    // 32KB: [buf][slot kvt*8+nb*2+kf][frag]

    // staging: each of 8 waves stages 2 K slots and 2 V slots per step (role-independent)
    auto issueK = [&](int st, int buf) {
#pragma unroll
        for (int i = 0; i < 2; ++i) {
            const int j = wv*2 + i;                 // 0..15
            const int nt = j >> 1, kf = j & 1;
            const __bf16* gk = kF + ((((size_t)b*128 + st*8 + nt)*16 + h)*2 + kf)*512 + (size_t)ln*8;
            gload_lds16(gk, &Ks[buf][j*512]);
        }
    };
    auto issueV = [&](int st, int buf) {
#pragma unroll
        for (int i = 0; i < 2; ++i) {
            const int j = wv*2 + i;                 // 0..15
            const int kvt = j >> 3, nb = (j >> 1) & 3, kf = j & 1;
            const __bf16* gv = vF + ((((size_t)bh*32 + st*2 + kvt)*4 + nb)*2 + kf)*512 + (size_t)ln*8;
            gload_lds16(gv, &Vs[buf][j*512]);
        }
    };

    // Q fragments for both 16-row halves, pre-scaled by 0.125*log2(e) so P = exp2(S)
    const float qscale = 0.125f * 1.44269504088896f;
    bf16x8 qf[2][2];                                // [hf][kf]
#pragma unroll
    for (int hf = 0; hf < 2; ++hf)
#pragma unroll
        for (int kf = 0; kf < 2; ++kf) {
            bf16x8 t = *(const bf16x8*)&qF[((((size_t)b*128 + (q0w >> 4) + hf)*16 + h)*2 + kf)*512 + ln*8];
#pragma unroll
            for (int j = 0; j < 8; ++j) t[j] = (__bf16)((float)t[j] * qscale);
            qf[hf][kf] = t;
        }
    bf16x8 ones;
#pragma unroll
    for (int j = 0; j < 8; ++j) ones[j] = (__bf16)1.0f;

    f32x4 o[2][4] = {};                             // [hf] partial O^T (dv=nb*16+quad*4+r, q=lm)
    f32x4 o5[2] = {};                               // [hf] partial l
    bf16x8 pf[2][2];                                // loop-carried P frags [hf][kfl]
    const int nsteps = ty + 1;                      // 128-kv tiles

    auto act = [&](int st) { return st*128 + h1*64 <= q0w + 31; };  // wave-uniform

    // QK + softmax of this wave's kv-half of tile (cur buffer) -> pf
    auto qk_sm = [&](int cur, int kv0, bool domask) {
        f32x4 s[2][4] = {};
        __builtin_amdgcn_s_setprio(1);
#pragma unroll
        for (int nt4 = 0; nt4 < 4; ++nt4) {
            const int nt = h1*4 + nt4;
            bf16x8 k0 = *(const bf16x8*)&Ks[cur][(nt*2 + 0)*512 + ln*8];
            bf16x8 k1 = *(const bf16x8*)&Ks[cur][(nt*2 + 1)*512 + ln*8];
            s[0][nt4] = __builtin_amdgcn_mfma_f32_16x16x32_bf16(k0, qf[0][0], s[0][nt4], 0, 0, 0);
            s[0][nt4] = __builtin_amdgcn_mfma_f32_16x16x32_bf16(k1, qf[0][1], s[0][nt4], 0, 0, 0);
            s[1][nt4] = __builtin_amdgcn_mfma_f32_16x16x32_bf16(k0, qf[1][0], s[1][nt4], 0, 0, 0);
            s[1][nt4] = __builtin_amdgcn_mfma_f32_16x16x32_bf16(k1, qf[1][1], s[1][nt4], 0, 0, 0);
        }
        __builtin_amdgcn_s_setprio(0);
        if (domask) {                               // diagonal step only; exp2(-1e9)=0
#pragma unroll
            for (int hf = 0; hf < 2; ++hf) {
                const int qg = q0w + hf*16 + lm;
#pragma unroll
                for (int nt4 = 0; nt4 < 4; ++nt4)
#pragma unroll
                    for (int r = 0; r < 4; ++r) {
                        int kvg = kv0 + h1*64 + nt4*16 + quad*4 + r;
                        if (kvg > qg) s[hf][nt4][r] = -1e9f;
                    }
            }
        }
        // per q-half: exp2 + pack to bf16 dwords, then quad-exchange (register-only)
#pragma unroll
        for (int hf = 0; hf < 2; ++hf) {
            unsigned d4[4][2];
#pragma unroll
            for (int nt4 = 0; nt4 < 4; ++nt4)
#pragma unroll
                for (int p = 0; p < 2; ++p) {
                    bf16x2 t;
                    t[0] = (__bf16)fast_exp2(s[hf][nt4][2*p]);
                    t[1] = (__bf16)fast_exp2(s[hf][nt4][2*p + 1]);
                    d4[nt4][p] = __builtin_bit_cast(unsigned, t);
                }
#pragma unroll
            for (int kfl = 0; kfl < 2; ++kfl) {
                unsigned w[4];
#pragma unroll
                for (int p = 0; p < 2; ++p) {
                    unsigned r0 = d4[kfl*2 + 0][p];
                    unsigned r1 = d4[kfl*2 + 1][p];
                    asm volatile("v_permlane32_swap_b32 %0, %1" : "+v"(r0), "+v"(r1));
                    asm volatile("v_permlane16_swap_b32 %0, %1" : "+v"(r0), "+v"(r1));
                    w[p]     = r0;
                    w[2 + p] = r1;
                }
                union { unsigned u[4]; bf16x8 v; } cvt;
                cvt.u[0] = w[0]; cvt.u[1] = w[1]; cvt.u[2] = w[2]; cvt.u[3] = w[3];
                pf[hf][kfl] = cvt.v;
            }
        }
    };

    // PV of this wave's kv-half of the tile whose V sits in Vs[vb], P in pf
    auto pv = [&](int vb) {
        __builtin_amdgcn_s_setprio(1);
#pragma unroll
        for (int nb = 0; nb < 4; ++nb)
#pragma unroll
            for (int kfl = 0; kfl < 2; ++kfl) {
                bf16x8 vf = *(const bf16x8*)&Vs[vb][(h1*8 + nb*2 + kfl)*512 + ln*8];
                o[0][nb] = __builtin_amdgcn_mfma_f32_16x16x32_bf16(vf, pf[0][kfl], o[0][nb], 0, 0, 0);
                o[1][nb] = __builtin_amdgcn_mfma_f32_16x16x32_bf16(vf, pf[1][kfl], o[1][nb], 0, 0, 0);
            }
#pragma unroll
        for (int hf = 0; hf < 2; ++hf)
#pragma unroll
            for (int kfl = 0; kfl < 2; ++kfl)
                o5[hf] = __builtin_amdgcn_mfma_f32_16x16x32_bf16(ones, pf[hf][kfl], o5[hf], 0, 0, 0);
        __builtin_amdgcn_s_setprio(0);
    };

    // ---- pipelined main loop (PV of tile st-1 overlaps QK of tile st)
    issueK(0, 0);
    __syncthreads();                                // drains K[0]
    if (nsteps > 1) issueK(1, 1);
    issueV(0, 0);
    if (act(0)) qk_sm(0, 0, nsteps == 1);           // -> pf of tile 0

    for (int st = 1; st < nsteps; ++st) {
        const int cur = st & 1;
        __syncthreads();                            // drains K[st] and V[st-1]
        if (st + 1 < nsteps) issueK(st + 1, cur ^ 1);
        issueV(st, cur);
        pv(cur ^ 1);                                // PV of tile st-1 (always active)
        if (act(st)) qk_sm(cur, st * 128, st == nsteps - 1);
    }

    __syncthreads();                                // drains V[nsteps-1]
    if (act(nsteps - 1)) pv((nsteps - 1) & 1);      // drain pipeline

    // ---- combine kv-halves through LDS scratch (aliases Ks/Vs; all compute is done)
    float* oscr = (float*)&Ks[0][0];                // 32KB: [qg2][hf][nb][lane] f32x4
    float* lscr = (float*)&Vs[0][0];                // 2KB:  [qg2][hf][lane]
    __syncthreads();                                // everyone done reading Ks/Vs
    if (h1 == 1) {
#pragma unroll
        for (int hf = 0; hf < 2; ++hf) {
#pragma unroll
            for (int nb = 0; nb < 4; ++nb)
                *(f32x4*)&oscr[((((qg2*2 + hf)*4 + nb)*64) + ln)*4] = o[hf][nb];
            lscr[(qg2*2 + hf)*64 + ln] = o5[hf][0];
        }
    }
    __syncthreads();
    if (h1 == 0) {
#pragma unroll
        for (int hf = 0; hf < 2; ++hf) {
            const float l = o5[hf][0] + lscr[(qg2*2 + hf)*64 + ln];
            const float invl = 1.0f / l;
            float* orow = out + (size_t)(b*SEQ + q0w + hf*16 + lm)*DIM + h*64;
#pragma unroll
            for (int nb = 0; nb < 4; ++nb) {
                f32x4 part = *(const f32x4*)&oscr[((((qg2*2 + hf)*4 + nb)*64) + ln)*4];
                float4 vres;
                vres.x = (o[hf][nb][0] + part[0]) * invl;
                vres.y = (o[hf][nb][1] + part[1]) * invl;
                vres.z = (o[hf][nb][2] + part[2]) * invl;
                vres.w = (o[hf][nb][3] + part[3]) * invl;
                *(float4*)&orow[nb*16 + quad*4] = vres;
            }
        }
    }
}

// ---------------------------------------------------------------- launcher
extern "C" void kernel_launch(void* const* d_in, const int* in_sizes, int n_in,
                              void* d_out, int out_size, void* d_ws, size_t ws_size,
                              hipStream_t stream) {
    const float* x   = (const float*)d_in[0];
    const float* Wqk = (const float*)d_in[1];
    const float* bqk = (const float*)d_in[2];
    const float* Wv  = (const float*)d_in[3];
    const float* bv  = (const float*)d_in[4];
    float* out = (float*)d_out;

    char* ws = (char*)d_ws;
    const size_t SZ_XB = (size_t)MROWS*KDIM*2;    // 8 MB
    const size_t SZ_WT = (size_t)NTOT*KDIM*2;     // 6 MB
    const size_t SZ_F  = (size_t)MROWS*1024*2;    // 8 MB per frag buffer
    __bf16* xb = (__bf16*)(ws);
    __bf16* Wt = (__bf16*)(ws + SZ_XB);
    __bf16* qF = (__bf16*)(ws + SZ_XB + SZ_WT);
    __bf16* kF = (__bf16*)(ws + SZ_XB + SZ_WT + SZ_F);
    __bf16* vF = (__bf16*)(ws + SZ_XB + SZ_WT + 2*SZ_F);

    prep_kernel    <<<4096 + 768, 256, 0, stream>>>(x, Wqk, Wv, xb, Wt);
    gemm_qkv_kernel<<<dim3(NTOT/BN, MROWS/BM), 256, 0, stream>>>(xb, Wt, bqk, bv, qF, kF, vF);
    attn_kernel    <<<dim3(32, 16), 512, 0, stream>>>(qF, kF, vF, out);
}

// Round 10
// 152.119 us; speedup vs baseline: 1.0084x; 1.0084x over previous
//
#include <hip/hip_runtime.h>
#include <hip/hip_bf16.h>
#include <math.h>

// Problem constants
#define BATCH 2
#define SEQ   2048
#define DIM   1024
#define HEADS 16
#define DH    64
#define MROWS (BATCH*SEQ)      // 4096
#define NTOT  3072             // gemm output cols: q(1024) | k(1024) | v(1024)
#define KDIM  1024

typedef float f32x4 __attribute__((ext_vector_type(4)));
typedef __bf16 bf16x8 __attribute__((ext_vector_type(8)));
typedef __bf16 bf16x4 __attribute__((ext_vector_type(4)));
typedef __bf16 bf16x2 __attribute__((ext_vector_type(2)));

// Fragment-order buffers (1KB block = 64 lanes x 16B chunk, lane ln = featquad*16 + (token&15)):
//  qF/kF: block index ((b*128 + g)*16 + h)*2 + kf      g = token-group (16 tokens)
//  vF   : block index ((bh*32 + kvt)*4 + nb)*2 + kf    kvt = kv/64, dv-group nb
// One 1KB block == one wave64 global_load_lds (base + ln*16B) == one b128 LDS frag read.

__device__ __forceinline__ void gload_lds16(const void* g, void* l) {
    __builtin_amdgcn_global_load_lds((__attribute__((address_space(1))) void*)g,
                                     (__attribute__((address_space(3))) void*)l,
                                     16, 0, 0);
}

// raw v_exp_f32: skips OCML exp2f's denormal-fixup sequence. Validated v15/v16/v17b.
__device__ __forceinline__ float fast_exp2(float x) {
    float r;
    asm("v_exp_f32 %0, %1" : "=v"(r) : "v"(x));
    return r;
}

// ---------------------------------------------- prep: cast x -> bf16  +  transpose W -> Wt
__global__ void prep_kernel(const float* __restrict__ x,
                            const float* __restrict__ Wqk, const float* __restrict__ Wv,
                            __bf16* __restrict__ xb, __bf16* __restrict__ Wt) {
    __shared__ float T[64*65];
    const int bx = blockIdx.x;
    const int tid = threadIdx.x;
    if (bx < 4096) {
        int i = bx * 256 + tid;                   // 1M float4 = 4M floats exactly
        float4 f = ((const float4*)x)[i];
        bf16x4 o;
        o.x = (__bf16)f.x; o.y = (__bf16)f.y; o.z = (__bf16)f.z; o.w = (__bf16)f.w;
        ((bf16x4*)xb)[i] = o;
    } else {
        const int t = bx - 4096;                  // 0..767
        const int n0 = (t % 48) * 64;
        const int k0 = (t / 48) * 64;
#pragma unroll
        for (int i = 0; i < 16; ++i) {
            int idx = i*256 + tid;
            int kk = idx >> 6, nn = idx & 63;
            int n = n0 + nn;
            float v = (n < 2048) ? Wqk[(size_t)(k0+kk)*2048 + n]
                                 : Wv [(size_t)(k0+kk)*1024 + (n - 2048)];
            T[kk*65 + nn] = v;
        }
        __syncthreads();
#pragma unroll
        for (int i = 0; i < 16; ++i) {
            int idx = i*256 + tid;
            int nn = idx >> 6, kk = idx & 63;
            Wt[(size_t)(n0+nn)*KDIM + k0 + kk] = (__bf16)T[kk*65 + nn];
        }
    }
}

// ---------------------------------------------------------------- GEMM v6 (r11, unchanged)
#define BM 128
#define BN 128
#define BK 64

__global__ __launch_bounds__(256) void gemm_qkv_kernel(const __bf16* __restrict__ A,
                                                       const __bf16* __restrict__ Bt,
                                                       const float* __restrict__ bqk,
                                                       const float* __restrict__ bv,
                                                       __bf16* __restrict__ qF,
                                                       __bf16* __restrict__ kF,
                                                       __bf16* __restrict__ vF) {
    __shared__ alignas(16) __bf16 As[BM*BK];
    __shared__ alignas(16) __bf16 Bs[BN*BK];
    const int tid = threadIdx.x;
    const int wv = tid >> 6, ln = tid & 63;
    const int quad = ln >> 4, lm = ln & 15;
    const int m0 = blockIdx.y * BM, n0 = blockIdx.x * BN;
    const int wm = (wv >> 1) * 64, wn = (wv & 1) * 64;
    const int sw = lm & 7;

    f32x4 acc[4][4] = {};

    if (n0 < 2048) {
        // ---------------- q/k path: acc[nt][mt] = C^T tiles ----------------
        for (int kt = 0; kt < KDIM/BK; ++kt) {
            const int k0 = kt * BK;
            __syncthreads();
#pragma unroll
            for (int i = 0; i < 4; ++i) {
                int slot = wv*256 + i*64 + ln;
                int row = slot >> 3, p = slot & 7;
                int cc = (p ^ (row & 7)) * 8;
                gload_lds16(A  + (size_t)(m0 + row)*KDIM + k0 + cc, &As[(wv*256 + i*64)*8]);
                gload_lds16(Bt + (size_t)(n0 + row)*KDIM + k0 + cc, &Bs[(wv*256 + i*64)*8]);
            }
            __syncthreads();
#pragma unroll
            for (int kf = 0; kf < 2; ++kf) {
                bf16x8 af[4], bfr[4];
#pragma unroll
                for (int mt = 0; mt < 4; ++mt)
                    af[mt] = *(const bf16x8*)&As[(wm + mt*16 + lm)*BK + (((kf<<2)|quad) ^ sw)*8];
#pragma unroll
                for (int nt = 0; nt < 4; ++nt)
                    bfr[nt] = *(const bf16x8*)&Bs[(wn + nt*16 + lm)*BK + (((kf<<2)|quad) ^ sw)*8];
#pragma unroll
                for (int nt = 0; nt < 4; ++nt)
#pragma unroll
                    for (int mt = 0; mt < 4; ++mt)
                        acc[nt][mt] = __builtin_amdgcn_mfma_f32_16x16x32_bf16(bfr[nt], af[mt], acc[nt][mt], 0, 0, 0);
            }
        }
        __bf16* dst = (n0 < 1024) ? qF : kF;        // block-uniform
#pragma unroll
        for (int nt = 0; nt < 4; ++nt) {
            int f = n0 + wn + nt*16 + quad*4;
            float4 bs4 = *(const float4*)&bqk[f];
            int fl = f & 1023;
            int h  = fl >> 6;
            int ff = fl & 63;
            int fquad = (ff >> 3) & 3;
            int j0 = ff & 7;
            int kf = ff >> 5;
#pragma unroll
            for (int mt = 0; mt < 4; ++mt) {
                int m = m0 + wm + mt*16 + lm;
                int b = m >> 11, g = (m & 2047) >> 4;
                bf16x4 pk;
                pk[0] = (__bf16)(acc[nt][mt][0] + bs4.x);
                pk[1] = (__bf16)(acc[nt][mt][1] + bs4.y);
                pk[2] = (__bf16)(acc[nt][mt][2] + bs4.z);
                pk[3] = (__bf16)(acc[nt][mt][3] + bs4.w);
                size_t blk = (((size_t)(b*128 + g)*16 + h)*2 + kf);
                *(bf16x4*)&dst[blk*512 + (fquad*16 + lm)*8 + j0] = pk;
            }
        }
    } else {
        // ---------------- v path: acc[mt][nt] = C tiles -> vF frag-order ----------------
        for (int kt = 0; kt < KDIM/BK; ++kt) {
            const int k0 = kt * BK;
            __syncthreads();
#pragma unroll
            for (int i = 0; i < 4; ++i) {
                int slot = wv*256 + i*64 + ln;
                int row = slot >> 3, p = slot & 7;
                int cc = (p ^ (row & 7)) * 8;
                gload_lds16(A  + (size_t)(m0 + row)*KDIM + k0 + cc, &As[(wv*256 + i*64)*8]);
                gload_lds16(Bt + (size_t)(n0 + row)*KDIM + k0 + cc, &Bs[(wv*256 + i*64)*8]);
            }
            __syncthreads();
#pragma unroll
            for (int kf = 0; kf < 2; ++kf) {
                bf16x8 af[4], bfr[4];
#pragma unroll
                for (int mt = 0; mt < 4; ++mt)
                    af[mt] = *(const bf16x8*)&As[(wm + mt*16 + lm)*BK + (((kf<<2)|quad) ^ sw)*8];
#pragma unroll
                for (int nt = 0; nt < 4; ++nt)
                    bfr[nt] = *(const bf16x8*)&Bs[(wn + nt*16 + lm)*BK + (((kf<<2)|quad) ^ sw)*8];
#pragma unroll
                for (int mt = 0; mt < 4; ++mt)
#pragma unroll
                    for (int nt = 0; nt < 4; ++nt)
                        acc[mt][nt] = __builtin_amdgcn_mfma_f32_16x16x32_bf16(af[mt], bfr[nt], acc[mt][nt], 0, 0, 0);
            }
        }
#pragma unroll
        for (int mt = 0; mt < 4; ++mt) {
            int s4 = m0 + wm + mt*16 + quad*4;
            int b   = s4 >> 11;
            int kvt = (s4 & 2047) >> 6;
            int kv  = s4 & 63;
            int kf  = kv >> 5;
            int qv  = (kv >> 3) & 3;
            int j0  = kv & 7;
#pragma unroll
            for (int nt = 0; nt < 4; ++nt) {
                int cv = n0 + wn + nt*16 + lm - 2048;
                int h = cv >> 6, dv = cv & 63, nb = dv >> 4;
                float bs = bv[cv];
                bf16x4 pk;
#pragma unroll
                for (int r = 0; r < 4; ++r) pk[r] = (__bf16)(acc[mt][nt][r] + bs);
                size_t blk = (((size_t)((b*16 + h)*32 + kvt)*4 + nb)*2 + kf);
                *(bf16x4*)&vF[blk*512 + (qv*16 + lm)*8 + j0] = pk;
            }
        }
    }
}

// ---------------------------------------------------------------- flash attention v20
// v19 (kv-split: 8 waves = 4 q-groups x 2 kv-halves; V-reads halved) regressed 153 vs
// v18's 142.8 -- candidate causes: (a) VGPR spill (persistent state +36 regs, qk_sm peak
// s[2][4]+kfrags ~130 > 128 cap) or (b) container noise (r9 container pathological; rest-
// of-pipeline varies +-10us cross-container). v20 keeps the kv-split (sound theory: v18's
// 256KB LDS-reads/block-step = ~21us floor; split halves it) but ELIMINATES the spill
// mechanism: the two 16-row q-halves are processed SEQUENTIALLY in qk_sm -- QK(hf) ->
// mask -> exp2 -> permlane -> pf[hf], freeing s[4] before the next half. K frags re-read
// per half (24 b128/wave/step vs v19's 16, still 25% under v18's 32); peak regs ~123<128.
// Pre-commit: <=140 total => kv-split banked; >=150 healthy => revert to v18.
// All else = v19: PV pipeline, permlane P-redistribution, KVBLK=128, fast_exp2,
// LDS combine of kv-halves (f32, threshold has 3x headroom), act-gated tail tiles.

__global__ __launch_bounds__(512, 4) void attn_kernel(const __bf16* __restrict__ qF,
                                                      const __bf16* __restrict__ kF,
                                                      const __bf16* __restrict__ vF,
                                                      float* __restrict__ out) {
    const int bh = blockIdx.x;
    const int b = bh >> 4, h = bh & 15;
    const int tyr = blockIdx.y;                     // 0..15
    const int ty = (tyr < 8) ? (15 - tyr) : (tyr - 8);  // heavy-first + pairwise balanced
    const int qb = ty * 128;
    const int tid = threadIdx.x, wv = tid >> 6, ln = tid & 63;
    const int quad = ln >> 4, lm = ln & 15;
    const int qg2 = wv & 3;                         // q-group: 32 rows
    const int h1  = wv >> 2;                        // kv-half: 64 kv
    const int q0w = qb + qg2*32;                    // this wave's 32 q-rows (two 16-row frags)

    __shared__ alignas(16) __bf16 Ks[2][16*512];    // 32KB: [buf][slot nt*2+kf][frag]
    __shared__ alignas(16) __bf16 Vs[2][16*512];    // 32KB: [buf][slot kvt*8+nb*2+kf][frag]

    // staging: each of 8 waves stages 2 K slots and 2 V slots per step (role-independent)
    auto issueK = [&](int st, int buf) {
#pragma unroll
        for (int i = 0; i < 2; ++i) {
            const int j = wv*2 + i;                 // 0..15
            const int nt = j >> 1, kf = j & 1;
            const __bf16* gk = kF + ((((size_t)b*128 + st*8 + nt)*16 + h)*2 + kf)*512 + (size_t)ln*8;
            gload_lds16(gk, &Ks[buf][j*512]);
        }
    };
    auto issueV = [&](int st, int buf) {
#pragma unroll
        for (int i = 0; i < 2; ++i) {
            const int j = wv*2 + i;                 // 0..15
            const int kvt = j >> 3, nb = (j >> 1) & 3, kf = j & 1;
            const __bf16* gv = vF + ((((size_t)bh*32 + st*2 + kvt)*4 + nb)*2 + kf)*512 + (size_t)ln*8;
            gload_lds16(gv, &Vs[buf][j*512]);
        }
    };

    // Q fragments for both 16-row halves, pre-scaled by 0.125*log2(e) so P = exp2(S)
    const float qscale = 0.125f * 1.44269504088896f;
    bf16x8 qf[2][2];                                // [hf][kf]
#pragma unroll
    for (int hf = 0; hf < 2; ++hf)
#pragma unroll
        for (int kf = 0; kf < 2; ++kf) {
            bf16x8 t = *(const bf16x8*)&qF[((((size_t)b*128 + (q0w >> 4) + hf)*16 + h)*2 + kf)*512 + ln*8];
#pragma unroll
            for (int j = 0; j < 8; ++j) t[j] = (__bf16)((float)t[j] * qscale);
            qf[hf][kf] = t;
        }
    bf16x8 ones;
#pragma unroll
    for (int j = 0; j < 8; ++j) ones[j] = (__bf16)1.0f;

    f32x4 o[2][4] = {};                             // [hf] partial O^T (dv=nb*16+quad*4+r, q=lm)
    f32x4 o5[2] = {};                               // [hf] partial l
    bf16x8 pf[2][2];                                // loop-carried P frags [hf][kfl]
    const int nsteps = ty + 1;                      // 128-kv tiles

    auto act = [&](int st) { return st*128 + h1*64 <= q0w + 31; };  // wave-uniform

    // QK + softmax of this wave's kv-half of tile (cur buffer) -> pf.
    // Two q-halves SEQUENTIAL: s[4] (16 regs) freed between halves (anti-spill, v20).
    auto qk_sm = [&](int cur, int kv0, bool domask) {
#pragma unroll
        for (int hf = 0; hf < 2; ++hf) {
            f32x4 s[4] = {};
            __builtin_amdgcn_s_setprio(1);
#pragma unroll
            for (int nt4 = 0; nt4 < 4; ++nt4) {
                const int nt = h1*4 + nt4;
                bf16x8 k0 = *(const bf16x8*)&Ks[cur][(nt*2 + 0)*512 + ln*8];
                bf16x8 k1 = *(const bf16x8*)&Ks[cur][(nt*2 + 1)*512 + ln*8];
                s[nt4] = __builtin_amdgcn_mfma_f32_16x16x32_bf16(k0, qf[hf][0], s[nt4], 0, 0, 0);
                s[nt4] = __builtin_amdgcn_mfma_f32_16x16x32_bf16(k1, qf[hf][1], s[nt4], 0, 0, 0);
            }
            __builtin_amdgcn_s_setprio(0);
            if (domask) {                           // diagonal step only; exp2(-1e9)=0
                const int qg = q0w + hf*16 + lm;
#pragma unroll
                for (int nt4 = 0; nt4 < 4; ++nt4)
#pragma unroll
                    for (int r = 0; r < 4; ++r) {
                        int kvg = kv0 + h1*64 + nt4*16 + quad*4 + r;
                        if (kvg > qg) s[nt4][r] = -1e9f;
                    }
            }
            unsigned d4[4][2];
#pragma unroll
            for (int nt4 = 0; nt4 < 4; ++nt4)
#pragma unroll
                for (int p = 0; p < 2; ++p) {
                    bf16x2 t;
                    t[0] = (__bf16)fast_exp2(s[nt4][2*p]);
                    t[1] = (__bf16)fast_exp2(s[nt4][2*p + 1]);
                    d4[nt4][p] = __builtin_bit_cast(unsigned, t);
                }
#pragma unroll
            for (int kfl = 0; kfl < 2; ++kfl) {
                unsigned w[4];
#pragma unroll
                for (int p = 0; p < 2; ++p) {
                    unsigned r0 = d4[kfl*2 + 0][p];
                    unsigned r1 = d4[kfl*2 + 1][p];
                    asm volatile("v_permlane32_swap_b32 %0, %1" : "+v"(r0), "+v"(r1));
                    asm volatile("v_permlane16_swap_b32 %0, %1" : "+v"(r0), "+v"(r1));
                    w[p]     = r0;
                    w[2 + p] = r1;
                }
                union { unsigned u[4]; bf16x8 v; } cvt;
                cvt.u[0] = w[0]; cvt.u[1] = w[1]; cvt.u[2] = w[2]; cvt.u[3] = w[3];
                pf[hf][kfl] = cvt.v;
            }
        }
    };

    // PV of this wave's kv-half of the tile whose V sits in Vs[vb], P in pf
    auto pv = [&](int vb) {
        __builtin_amdgcn_s_setprio(1);
#pragma unroll
        for (int nb = 0; nb < 4; ++nb)
#pragma unroll
            for (int kfl = 0; kfl < 2; ++kfl) {
                bf16x8 vf = *(const bf16x8*)&Vs[vb][(h1*8 + nb*2 + kfl)*512 + ln*8];
                o[0][nb] = __builtin_amdgcn_mfma_f32_16x16x32_bf16(vf, pf[0][kfl], o[0][nb], 0, 0, 0);
                o[1][nb] = __builtin_amdgcn_mfma_f32_16x16x32_bf16(vf, pf[1][kfl], o[1][nb], 0, 0, 0);
            }
#pragma unroll
        for (int hf = 0; hf < 2; ++hf)
#pragma unroll
            for (int kfl = 0; kfl < 2; ++kfl)
                o5[hf] = __builtin_amdgcn_mfma_f32_16x16x32_bf16(ones, pf[hf][kfl], o5[hf], 0, 0, 0);
        __builtin_amdgcn_s_setprio(0);
    };

    // ---- pipelined main loop (PV of tile st-1 overlaps QK of tile st)
    issueK(0, 0);
    __syncthreads();                                // drains K[0]
    if (nsteps > 1) issueK(1, 1);
    issueV(0, 0);
    if (act(0)) qk_sm(0, 0, nsteps == 1);           // -> pf of tile 0

    for (int st = 1; st < nsteps; ++st) {
        const int cur = st & 1;
        __syncthreads();                            // drains K[st] and V[st-1]
        if (st + 1 < nsteps) issueK(st + 1, cur ^ 1);
        issueV(st, cur);
        pv(cur ^ 1);                                // PV of tile st-1 (tiles 0..nsteps-2 all active)
        if (act(st)) qk_sm(cur, st * 128, st == nsteps - 1);
    }

    __syncthreads();                                // drains V[nsteps-1]
    if (act(nsteps - 1)) pv((nsteps - 1) & 1);      // drain pipeline

    // ---- combine kv-halves through LDS scratch (aliases Ks/Vs; all compute is done)
    float* oscr = (float*)&Ks[0][0];                // 32KB: [qg2][hf][nb][lane] f32x4
    float* lscr = (float*)&Vs[0][0];                // 2KB:  [qg2][hf][lane]
    __syncthreads();                                // everyone done reading Ks/Vs
    if (h1 == 1) {
#pragma unroll
        for (int hf = 0; hf < 2; ++hf) {
#pragma unroll
            for (int nb = 0; nb < 4; ++nb)
                *(f32x4*)&oscr[((((qg2*2 + hf)*4 + nb)*64) + ln)*4] = o[hf][nb];
            lscr[(qg2*2 + hf)*64 + ln] = o5[hf][0];
        }
    }
    __syncthreads();
    if (h1 == 0) {
#pragma unroll
        for (int hf = 0; hf < 2; ++hf) {
            const float l = o5[hf][0] + lscr[(qg2*2 + hf)*64 + ln];
            const float invl = 1.0f / l;
            float* orow = out + (size_t)(b*SEQ + q0w + hf*16 + lm)*DIM + h*64;
#pragma unroll
            for (int nb = 0; nb < 4; ++nb) {
                f32x4 part = *(const f32x4*)&oscr[((((qg2*2 + hf)*4 + nb)*64) + ln)*4];
                float4 vres;
                vres.x = (o[hf][nb][0] + part[0]) * invl;
                vres.y = (o[hf][nb][1] + part[1]) * invl;
                vres.z = (o[hf][nb][2] + part[2]) * invl;
                vres.w = (o[hf][nb][3] + part[3]) * invl;
                *(float4*)&orow[nb*16 + quad*4] = vres;
            }
        }
    }
}

// ---------------------------------------------------------------- launcher
extern "C" void kernel_launch(void* const* d_in, const int* in_sizes, int n_in,
                              void* d_out, int out_size, void* d_ws, size_t ws_size,
                              hipStream_t stream) {
    const float* x   = (const float*)d_in[0];
    const float* Wqk = (const float*)d_in[1];
    const float* bqk = (const float*)d_in[2];
    const float* Wv  = (const float*)d_in[3];
    const float* bv  = (const float*)d_in[4];
    float* out = (float*)d_out;

    char* ws = (char*)d_ws;
    const size_t SZ_XB = (size_t)MROWS*KDIM*2;    // 8 MB
    const size_t SZ_WT = (size_t)NTOT*KDIM*2;     // 6 MB
    const size_t SZ_F  = (size_t)MROWS*1024*2;    // 8 MB per frag buffer
    __bf16* xb = (__bf16*)(ws);
    __bf16* Wt = (__bf16*)(ws + SZ_XB);
    __bf16* qF = (__bf16*)(ws + SZ_XB + SZ_WT);
    __bf16* kF = (__bf16*)(ws + SZ_XB + SZ_WT + SZ_F);
    __bf16* vF = (__bf16*)(ws + SZ_XB + SZ_WT + 2*SZ_F);

    prep_kernel    <<<4096 + 768, 256, 0, stream>>>(x, Wqk, Wv, xb, Wt);
    gemm_qkv_kernel<<<dim3(NTOT/BN, MROWS/BM), 256, 0, stream>>>(xb, Wt, bqk, bv, qF, kF, vF);
    attn_kernel    <<<dim3(32, 16), 512, 0, stream>>>(qF, kF, vF, out);
}

// Round 11
// 145.150 us; speedup vs baseline: 1.0568x; 1.0480x over previous
//
#include <hip/hip_runtime.h>
#include <hip/hip_bf16.h>
#include <math.h>

// Problem constants
#define BATCH 2
#define SEQ   2048
#define DIM   1024
#define HEADS 16
#define DH    64
#define MROWS (BATCH*SEQ)      // 4096
#define NTOT  3072             // gemm output cols: q(1024) | k(1024) | v(1024)
#define KDIM  1024

typedef float f32x4 __attribute__((ext_vector_type(4)));
typedef __bf16 bf16x8 __attribute__((ext_vector_type(8)));
typedef __bf16 bf16x4 __attribute__((ext_vector_type(4)));
typedef __bf16 bf16x2 __attribute__((ext_vector_type(2)));

// Fragment-order buffers (1KB block = 64 lanes x 16B chunk, lane ln = featquad*16 + (token&15)):
//  qF/kF: block index ((b*128 + g)*16 + h)*2 + kf      g = token-group (16 tokens)
//  vF   : block index ((bh*32 + kvt)*4 + nb)*2 + kf    kvt = kv/64, dv-group nb
// One 1KB block == one wave64 global_load_lds (base + ln*16B) == one b128 LDS frag read.

__device__ __forceinline__ void gload_lds16(const void* g, void* l) {
    __builtin_amdgcn_global_load_lds((__attribute__((address_space(1))) void*)g,
                                     (__attribute__((address_space(3))) void*)l,
                                     16, 0, 0);
}

// raw v_exp_f32: skips OCML exp2f's denormal-fixup sequence. Validated v15/v16/v17b/v18.
__device__ __forceinline__ float fast_exp2(float x) {
    float r;
    asm("v_exp_f32 %0, %1" : "=v"(r) : "v"(x));
    return r;
}

// ---------------------------------------------- prep: cast x -> bf16  +  transpose W -> Wt
__global__ void prep_kernel(const float* __restrict__ x,
                            const float* __restrict__ Wqk, const float* __restrict__ Wv,
                            __bf16* __restrict__ xb, __bf16* __restrict__ Wt) {
    __shared__ float T[64*65];
    const int bx = blockIdx.x;
    const int tid = threadIdx.x;
    if (bx < 4096) {
        int i = bx * 256 + tid;                   // 1M float4 = 4M floats exactly
        float4 f = ((const float4*)x)[i];
        bf16x4 o;
        o.x = (__bf16)f.x; o.y = (__bf16)f.y; o.z = (__bf16)f.z; o.w = (__bf16)f.w;
        ((bf16x4*)xb)[i] = o;
    } else {
        const int t = bx - 4096;                  // 0..767
        const int n0 = (t % 48) * 64;
        const int k0 = (t / 48) * 64;
#pragma unroll
        for (int i = 0; i < 16; ++i) {
            int idx = i*256 + tid;
            int kk = idx >> 6, nn = idx & 63;
            int n = n0 + nn;
            float v = (n < 2048) ? Wqk[(size_t)(k0+kk)*2048 + n]
                                 : Wv [(size_t)(k0+kk)*1024 + (n - 2048)];
            T[kk*65 + nn] = v;
        }
        __syncthreads();
#pragma unroll
        for (int i = 0; i < 16; ++i) {
            int idx = i*256 + tid;
            int nn = idx >> 6, kk = idx & 63;
            Wt[(size_t)(n0+nn)*KDIM + k0 + kk] = (__bf16)T[kk*65 + nn];
        }
    }
}

// ---------------------------------------------------------------- GEMM v6 (r11, unchanged)
#define BM 128
#define BN 128
#define BK 64

__global__ __launch_bounds__(256) void gemm_qkv_kernel(const __bf16* __restrict__ A,
                                                       const __bf16* __restrict__ Bt,
                                                       const float* __restrict__ bqk,
                                                       const float* __restrict__ bv,
                                                       __bf16* __restrict__ qF,
                                                       __bf16* __restrict__ kF,
                                                       __bf16* __restrict__ vF) {
    __shared__ alignas(16) __bf16 As[BM*BK];
    __shared__ alignas(16) __bf16 Bs[BN*BK];
    const int tid = threadIdx.x;
    const int wv = tid >> 6, ln = tid & 63;
    const int quad = ln >> 4, lm = ln & 15;
    const int m0 = blockIdx.y * BM, n0 = blockIdx.x * BN;
    const int wm = (wv >> 1) * 64, wn = (wv & 1) * 64;
    const int sw = lm & 7;

    f32x4 acc[4][4] = {};

    if (n0 < 2048) {
        // ---------------- q/k path: acc[nt][mt] = C^T tiles ----------------
        for (int kt = 0; kt < KDIM/BK; ++kt) {
            const int k0 = kt * BK;
            __syncthreads();
#pragma unroll
            for (int i = 0; i < 4; ++i) {
                int slot = wv*256 + i*64 + ln;
                int row = slot >> 3, p = slot & 7;
                int cc = (p ^ (row & 7)) * 8;
                gload_lds16(A  + (size_t)(m0 + row)*KDIM + k0 + cc, &As[(wv*256 + i*64)*8]);
                gload_lds16(Bt + (size_t)(n0 + row)*KDIM + k0 + cc, &Bs[(wv*256 + i*64)*8]);
            }
            __syncthreads();
#pragma unroll
            for (int kf = 0; kf < 2; ++kf) {
                bf16x8 af[4], bfr[4];
#pragma unroll
                for (int mt = 0; mt < 4; ++mt)
                    af[mt] = *(const bf16x8*)&As[(wm + mt*16 + lm)*BK + (((kf<<2)|quad) ^ sw)*8];
#pragma unroll
                for (int nt = 0; nt < 4; ++nt)
                    bfr[nt] = *(const bf16x8*)&Bs[(wn + nt*16 + lm)*BK + (((kf<<2)|quad) ^ sw)*8];
#pragma unroll
                for (int nt = 0; nt < 4; ++nt)
#pragma unroll
                    for (int mt = 0; mt < 4; ++mt)
                        acc[nt][mt] = __builtin_amdgcn_mfma_f32_16x16x32_bf16(bfr[nt], af[mt], acc[nt][mt], 0, 0, 0);
            }
        }
        __bf16* dst = (n0 < 1024) ? qF : kF;        // block-uniform
#pragma unroll
        for (int nt = 0; nt < 4; ++nt) {
            int f = n0 + wn + nt*16 + quad*4;
            float4 bs4 = *(const float4*)&bqk[f];
            int fl = f & 1023;
            int h  = fl >> 6;
            int ff = fl & 63;
            int fquad = (ff >> 3) & 3;
            int j0 = ff & 7;
            int kf = ff >> 5;
#pragma unroll
            for (int mt = 0; mt < 4; ++mt) {
                int m = m0 + wm + mt*16 + lm;
                int b = m >> 11, g = (m & 2047) >> 4;
                bf16x4 pk;
                pk[0] = (__bf16)(acc[nt][mt][0] + bs4.x);
                pk[1] = (__bf16)(acc[nt][mt][1] + bs4.y);
                pk[2] = (__bf16)(acc[nt][mt][2] + bs4.z);
                pk[3] = (__bf16)(acc[nt][mt][3] + bs4.w);
                size_t blk = (((size_t)(b*128 + g)*16 + h)*2 + kf);
                *(bf16x4*)&dst[blk*512 + (fquad*16 + lm)*8 + j0] = pk;
            }
        }
    } else {
        // ---------------- v path: acc[mt][nt] = C tiles -> vF frag-order ----------------
        for (int kt = 0; kt < KDIM/BK; ++kt) {
            const int k0 = kt * BK;
            __syncthreads();
#pragma unroll
            for (int i = 0; i < 4; ++i) {
                int slot = wv*256 + i*64 + ln;
                int row = slot >> 3, p = slot & 7;
                int cc = (p ^ (row & 7)) * 8;
                gload_lds16(A  + (size_t)(m0 + row)*KDIM + k0 + cc, &As[(wv*256 + i*64)*8]);
                gload_lds16(Bt + (size_t)(n0 + row)*KDIM + k0 + cc, &Bs[(wv*256 + i*64)*8]);
            }
            __syncthreads();
#pragma unroll
            for (int kf = 0; kf < 2; ++kf) {
                bf16x8 af[4], bfr[4];
#pragma unroll
                for (int mt = 0; mt < 4; ++mt)
                    af[mt] = *(const bf16x8*)&As[(wm + mt*16 + lm)*BK + (((kf<<2)|quad) ^ sw)*8];
#pragma unroll
                for (int nt = 0; nt < 4; ++nt)
                    bfr[nt] = *(const bf16x8*)&Bs[(wn + nt*16 + lm)*BK + (((kf<<2)|quad) ^ sw)*8];
#pragma unroll
                for (int mt = 0; mt < 4; ++mt)
#pragma unroll
                    for (int nt = 0; nt < 4; ++nt)
                        acc[mt][nt] = __builtin_amdgcn_mfma_f32_16x16x32_bf16(af[mt], bfr[nt], acc[mt][nt], 0, 0, 0);
            }
        }
#pragma unroll
        for (int mt = 0; mt < 4; ++mt) {
            int s4 = m0 + wm + mt*16 + quad*4;
            int b   = s4 >> 11;
            int kvt = (s4 & 2047) >> 6;
            int kv  = s4 & 63;
            int kf  = kv >> 5;
            int qv  = (kv >> 3) & 3;
            int j0  = kv & 7;
#pragma unroll
            for (int nt = 0; nt < 4; ++nt) {
                int cv = n0 + wn + nt*16 + lm - 2048;
                int h = cv >> 6, dv = cv & 63, nb = dv >> 4;
                float bs = bv[cv];
                bf16x4 pk;
#pragma unroll
                for (int r = 0; r < 4; ++r) pk[r] = (__bf16)(acc[mt][nt][r] + bs);
                size_t blk = (((size_t)((b*16 + h)*32 + kvt)*4 + nb)*2 + kf);
                *(bf16x4*)&vF[blk*512 + (qv*16 + lm)*8 + j0] = pk;
            }
        }
    }
}

// ---------------------------------------------------------------- flash attention v21
// = v18 (banked best, 142.8us) reverted per r9 pre-commit. kv-split (v19/v20) is
// EMPIRICALLY REFUTED: spill-safe v20 on a healthy container = 152.1 ~= v19's 153.4;
// the split's act-gated idle waves on diagonal steps + combine barriers cost more than
// the 25% LDS-read saving -> attn is latency/serialization-shaped, not LDS-BW-floor.
// Only delta vs v18: issue V[st] BEFORE K[st+1] each step (FIFO completion order matches
// consumption order next step: pv uses V first, qk uses K second). Zero-risk reorder of
// two wave-uniform load groups.
// Structure: 8-wave/512-thread blocks, 16 q-rows/wave, KVBLK=128 (17 steps/CU pairwise-
// balanced), one-tile PV pipeline (PV(st-1) at barrier-exit overlaps QK(st)), register-
// resident P via permlane quad-exchange, fast_exp2. LDS 64KB: Ks[2][16KB]+Vs[2][16KB].

__global__ __launch_bounds__(512, 4) void attn_kernel(const __bf16* __restrict__ qF,
                                                      const __bf16* __restrict__ kF,
                                                      const __bf16* __restrict__ vF,
                                                      float* __restrict__ out) {
    const int bh = blockIdx.x;
    const int b = bh >> 4, h = bh & 15;
    const int tyr = blockIdx.y;                     // 0..15
    const int ty = (tyr < 8) ? (15 - tyr) : (tyr - 8);  // heavy-first + pairwise balanced
    const int qb = ty * 128;
    const int tid = threadIdx.x, wv = tid >> 6, ln = tid & 63;
    const int quad = ln >> 4, lm = ln & 15;
    const int q0w = qb + wv*16;                     // this wave's 16 q-rows
    const int qg = q0w + lm;                        // this lane's q row

    __shared__ alignas(16) __bf16 Ks[2][16*512];    // 32KB: [buf][slot nt*2+kf][frag]
    __shared__ alignas(16) __bf16 Vs[2][16*512];    // 32KB: [buf][slot kvt*8+nb*2+kf][frag]

    // staging: each of 8 waves stages 2 K slots and 2 V slots per step (split issue)
    auto issueK = [&](int st, int buf) {
#pragma unroll
        for (int i = 0; i < 2; ++i) {
            const int j = wv*2 + i;                 // 0..15
            const int nt = j >> 1, kf = j & 1;
            const __bf16* gk = kF + ((((size_t)b*128 + st*8 + nt)*16 + h)*2 + kf)*512 + (size_t)ln*8;
            gload_lds16(gk, &Ks[buf][j*512]);
        }
    };
    auto issueV = [&](int st, int buf) {
#pragma unroll
        for (int i = 0; i < 2; ++i) {
            const int j = wv*2 + i;                 // 0..15
            const int kvt = j >> 3, nb = (j >> 1) & 3, kf = j & 1;
            const __bf16* gv = vF + ((((size_t)bh*32 + st*2 + kvt)*4 + nb)*2 + kf)*512 + (size_t)ln*8;
            gload_lds16(gv, &Vs[buf][j*512]);
        }
    };

    // Q fragments, pre-scaled by 0.125*log2(e) so P = exp2(S)
    const float qscale = 0.125f * 1.44269504088896f;
    bf16x8 qf[2];
#pragma unroll
    for (int kf = 0; kf < 2; ++kf) {
        bf16x8 t = *(const bf16x8*)&qF[((((size_t)b*128 + (q0w >> 4))*16 + h)*2 + kf)*512 + ln*8];
#pragma unroll
        for (int j = 0; j < 8; ++j) t[j] = (__bf16)((float)t[j] * qscale);
        qf[kf] = t;
    }
    bf16x8 ones;
#pragma unroll
    for (int j = 0; j < 8; ++j) ones[j] = (__bf16)1.0f;

    f32x4 o[4] = {};                                // O^T: (dv = nb*16+quad*4+r, q = lm)
    f32x4 o5 = {};                                  // l accumulator: every reg = l(q=lm)
    bf16x8 pf[4];                                   // loop-carried P fragments (tile st)
    const int nsteps = ty + 1;                      // 128-kv tiles

    // QK + softmax of tile (cur buffer), kv0 base, optional diagonal mask -> pf
    auto qk_sm = [&](int cur, int kv0, bool domask) {
        f32x4 s[8] = {};
        __builtin_amdgcn_s_setprio(1);
#pragma unroll
        for (int nt = 0; nt < 8; ++nt) {
            bf16x8 k0 = *(const bf16x8*)&Ks[cur][(nt*2 + 0)*512 + ln*8];
            bf16x8 k1 = *(const bf16x8*)&Ks[cur][(nt*2 + 1)*512 + ln*8];
            s[nt] = __builtin_amdgcn_mfma_f32_16x16x32_bf16(k0, qf[0], s[nt], 0, 0, 0);
            s[nt] = __builtin_amdgcn_mfma_f32_16x16x32_bf16(k1, qf[1], s[nt], 0, 0, 0);
        }
        __builtin_amdgcn_s_setprio(0);
        if (domask) {                               // diagonal step only; exp2(-1e9)=0
#pragma unroll
            for (int nt = 0; nt < 8; ++nt)
#pragma unroll
                for (int r = 0; r < 4; ++r) {
                    int kvg = kv0 + nt*16 + quad*4 + r;
                    if (kvg > qg) s[nt][r] = -1e9f;
                }
        }
        // per 64-kv group: exp2 + pack to bf16 dwords, then quad-exchange (register-only)
#pragma unroll
        for (int g = 0; g < 2; ++g) {
            unsigned d4[4][2];                      // d4[nt4][p] = (P[...,2p], P[...,2p+1])
#pragma unroll
            for (int nt4 = 0; nt4 < 4; ++nt4)
#pragma unroll
                for (int p = 0; p < 2; ++p) {
                    bf16x2 t;
                    t[0] = (__bf16)fast_exp2(s[g*4 + nt4][2*p]);
                    t[1] = (__bf16)fast_exp2(s[g*4 + nt4][2*p + 1]);
                    d4[nt4][p] = __builtin_bit_cast(unsigned, t);
                }
#pragma unroll
            for (int kfl = 0; kfl < 2; ++kfl) {
                unsigned w[4];
#pragma unroll
                for (int p = 0; p < 2; ++p) {
                    unsigned r0 = d4[kfl*2 + 0][p];
                    unsigned r1 = d4[kfl*2 + 1][p];
                    asm volatile("v_permlane32_swap_b32 %0, %1" : "+v"(r0), "+v"(r1));
                    asm volatile("v_permlane16_swap_b32 %0, %1" : "+v"(r0), "+v"(r1));
                    w[p]     = r0;
                    w[2 + p] = r1;
                }
                union { unsigned u[4]; bf16x8 v; } cvt;
                cvt.u[0] = w[0]; cvt.u[1] = w[1]; cvt.u[2] = w[2]; cvt.u[3] = w[3];
                pf[g*2 + kfl] = cvt.v;
            }
        }
    };

    // PV of the tile whose V sits in Vs[vb], P in pf
    auto pv = [&](int vb) {
        __builtin_amdgcn_s_setprio(1);
#pragma unroll
        for (int nb = 0; nb < 4; ++nb)
#pragma unroll
            for (int kfp = 0; kfp < 4; ++kfp) {
                bf16x8 vf = *(const bf16x8*)&Vs[vb][((kfp >> 1)*8 + nb*2 + (kfp & 1))*512 + ln*8];
                o[nb] = __builtin_amdgcn_mfma_f32_16x16x32_bf16(vf, pf[kfp], o[nb], 0, 0, 0);
            }
#pragma unroll
        for (int kfp = 0; kfp < 4; ++kfp)
            o5 = __builtin_amdgcn_mfma_f32_16x16x32_bf16(ones, pf[kfp], o5, 0, 0, 0);
        __builtin_amdgcn_s_setprio(0);
    };

    // ---- pipelined main loop (PV of tile st-1 overlaps QK of tile st)
    issueK(0, 0);
    __syncthreads();                                // drains K[0]
    issueV(0, 0);                                   // V first: consumed before K next step
    if (nsteps > 1) issueK(1, 1);
    qk_sm(0, 0, nsteps == 1);                       // -> pf of tile 0

    for (int st = 1; st < nsteps; ++st) {
        const int cur = st & 1;
        __syncthreads();                            // drains K[st] and V[st-1]
        issueV(st, cur);                            // V first (FIFO order = consumption order)
        if (st + 1 < nsteps) issueK(st + 1, cur ^ 1);
        pv(cur ^ 1);                                // PV of tile st-1 (operands ready now)
        qk_sm(cur, st * 128, st == nsteps - 1);     // -> pf of tile st
    }

    __syncthreads();                                // drains V[nsteps-1]
    pv((nsteps - 1) & 1);                           // drain pipeline

    // ---- epilogue: every lane holds l(q=lm) in o5
    const float invl = 1.0f / o5[0];
    float* orow = out + (size_t)(b*SEQ + q0w + lm)*DIM + h*64;
#pragma unroll
    for (int nb = 0; nb < 4; ++nb) {
        float4 vres;
        vres.x = o[nb][0] * invl;
        vres.y = o[nb][1] * invl;
        vres.z = o[nb][2] * invl;
        vres.w = o[nb][3] * invl;
        *(float4*)&orow[nb*16 + quad*4] = vres;
    }
}

// ---------------------------------------------------------------- launcher
extern "C" void kernel_launch(void* const* d_in, const int* in_sizes, int n_in,
                              void* d_out, int out_size, void* d_ws, size_t ws_size,
                              hipStream_t stream) {
    const float* x   = (const float*)d_in[0];
    const float* Wqk = (const float*)d_in[1];
    const float* bqk = (const float*)d_in[2];
    const float* Wv  = (const float*)d_in[3];
    const float* bv  = (const float*)d_in[4];
    float* out = (float*)d_out;

    char* ws = (char*)d_ws;
    const size_t SZ_XB = (size_t)MROWS*KDIM*2;    // 8 MB
    const size_t SZ_WT = (size_t)NTOT*KDIM*2;     // 6 MB
    const size_t SZ_F  = (size_t)MROWS*1024*2;    // 8 MB per frag buffer
    __bf16* xb = (__bf16*)(ws);
    __bf16* Wt = (__bf16*)(ws + SZ_XB);
    __bf16* qF = (__bf16*)(ws + SZ_XB + SZ_WT);
    __bf16* kF = (__bf16*)(ws + SZ_XB + SZ_WT + SZ_F);
    __bf16* vF = (__bf16*)(ws + SZ_XB + SZ_WT + 2*SZ_F);

    prep_kernel    <<<4096 + 768, 256, 0, stream>>>(x, Wqk, Wv, xb, Wt);
    gemm_qkv_kernel<<<dim3(NTOT/BN, MROWS/BM), 256, 0, stream>>>(xb, Wt, bqk, bv, qF, kF, vF);
    attn_kernel    <<<dim3(32, 16), 512, 0, stream>>>(qF, kF, vF, out);
}

// Round 12
// 141.052 us; speedup vs baseline: 1.0876x; 1.0291x over previous
//
#include <hip/hip_runtime.h>
#include <hip/hip_bf16.h>
#include <math.h>

// Problem constants
#define BATCH 2
#define SEQ   2048
#define DIM   1024
#define HEADS 16
#define DH    64
#define MROWS (BATCH*SEQ)      // 4096
#define NTOT  3072             // gemm output cols: q(1024) | k(1024) | v(1024)
#define KDIM  1024

typedef float f32x4 __attribute__((ext_vector_type(4)));
typedef __bf16 bf16x8 __attribute__((ext_vector_type(8)));
typedef __bf16 bf16x4 __attribute__((ext_vector_type(4)));
typedef __bf16 bf16x2 __attribute__((ext_vector_type(2)));

// Fragment-order buffers (1KB block = 64 lanes x 16B chunk, lane ln = featquad*16 + (token&15)):
//  qF/kF: block index ((b*128 + g)*16 + h)*2 + kf      g = token-group (16 tokens)
//  vF   : block index ((bh*32 + kvt)*4 + nb)*2 + kf    kvt = kv/64, dv-group nb
// One 1KB block == one wave64 global_load_lds (base + ln*16B) == one b128 LDS frag read.

__device__ __forceinline__ void gload_lds16(const void* g, void* l) {
    __builtin_amdgcn_global_load_lds((__attribute__((address_space(1))) void*)g,
                                     (__attribute__((address_space(3))) void*)l,
                                     16, 0, 0);
}

// raw v_exp_f32: skips OCML exp2f's denormal-fixup sequence. Validated v15/v16/v17b/v18.
__device__ __forceinline__ float fast_exp2(float x) {
    float r;
    asm("v_exp_f32 %0, %1" : "=v"(r) : "v"(x));
    return r;
}

// ---------------------------------------------- prep: cast x -> bf16  +  transpose W -> Wt
// v22: transpose phase vectorized (G13) -- loads float4 (16B/lane, was 4B scalar),
// stores bf16x4 (8B/lane, was 2B scalar). T keeps the 65-float row pad (bank-conflict-free).
__global__ void prep_kernel(const float* __restrict__ x,
                            const float* __restrict__ Wqk, const float* __restrict__ Wv,
                            __bf16* __restrict__ xb, __bf16* __restrict__ Wt) {
    __shared__ float T[64*65];
    const int bx = blockIdx.x;
    const int tid = threadIdx.x;
    if (bx < 4096) {
        int i = bx * 256 + tid;                   // 1M float4 = 4M floats exactly
        float4 f = ((const float4*)x)[i];
        bf16x4 o;
        o.x = (__bf16)f.x; o.y = (__bf16)f.y; o.z = (__bf16)f.z; o.w = (__bf16)f.w;
        ((bf16x4*)xb)[i] = o;
    } else {
        const int t = bx - 4096;                  // 0..767
        const int n0 = (t % 48) * 64;
        const int k0 = (t / 48) * 64;
        const bool isV = (n0 >= 2048);            // block-uniform
        const float* src = isV ? Wv : Wqk;
        const int stride = isV ? 1024 : 2048;
        const int ncol = isV ? (n0 - 2048) : n0;
#pragma unroll
        for (int i = 0; i < 4; ++i) {
            int idx = i*256 + tid;                // 0..1023
            int kk = idx >> 4;                    // 0..63
            int nn = (idx & 15) * 4;              // 0..60, float4-aligned
            float4 v = *(const float4*)&src[(size_t)(k0+kk)*stride + ncol + nn];
            T[kk*65 + nn + 0] = v.x;
            T[kk*65 + nn + 1] = v.y;
            T[kk*65 + nn + 2] = v.z;
            T[kk*65 + nn + 3] = v.w;
        }
        __syncthreads();
#pragma unroll
        for (int i = 0; i < 4; ++i) {
            int idx = i*256 + tid;
            int nn = idx >> 4;                    // 0..63
            int kk = (idx & 15) * 4;              // 0..60
            bf16x4 o;
            o[0] = (__bf16)T[(kk+0)*65 + nn];
            o[1] = (__bf16)T[(kk+1)*65 + nn];
            o[2] = (__bf16)T[(kk+2)*65 + nn];
            o[3] = (__bf16)T[(kk+3)*65 + nn];
            *(bf16x4*)&Wt[(size_t)(n0+nn)*KDIM + k0 + kk] = o;
        }
    }
}

// ---------------------------------------------------------------- GEMM v7: + XCD swizzle
#define BM 128
#define BN 128
#define BK 64

__global__ __launch_bounds__(256) void gemm_qkv_kernel(const __bf16* __restrict__ A,
                                                       const __bf16* __restrict__ Bt,
                                                       const float* __restrict__ bqk,
                                                       const float* __restrict__ bv,
                                                       __bf16* __restrict__ qF,
                                                       __bf16* __restrict__ kF,
                                                       __bf16* __restrict__ vF) {
    __shared__ alignas(16) __bf16 As[BM*BK];
    __shared__ alignas(16) __bf16 Bs[BN*BK];
    const int tid = threadIdx.x;
    const int wv = tid >> 6, ln = tid & 63;
    const int quad = ln >> 4, lm = ln & 15;
    // XCD-aware swizzle (T1): 768 blocks = 8 XCDs x 96 (bijective, 768%8==0). Each XCD
    // owns 3 B-panels x all 32 M-rows -> its Wt working set (0.75MB) is L2-resident
    // instead of thrashing across 8 incoherent per-XCD L2s. Perf-only remap.
    const int L = blockIdx.y * 24 + blockIdx.x;   // dispatch-linear (x fastest)
    const int xcd = L & 7, p = L >> 3;            // p in 0..95
    const int m0 = (p & 31) * BM;
    const int n0 = (3*xcd + (p >> 5)) * BN;
    const int wm = (wv >> 1) * 64, wn = (wv & 1) * 64;
    const int sw = lm & 7;

    f32x4 acc[4][4] = {};

    if (n0 < 2048) {
        // ---------------- q/k path: acc[nt][mt] = C^T tiles ----------------
        for (int kt = 0; kt < KDIM/BK; ++kt) {
            const int k0 = kt * BK;
            __syncthreads();
#pragma unroll
            for (int i = 0; i < 4; ++i) {
                int slot = wv*256 + i*64 + ln;
                int row = slot >> 3, pq = slot & 7;
                int cc = (pq ^ (row & 7)) * 8;
                gload_lds16(A  + (size_t)(m0 + row)*KDIM + k0 + cc, &As[(wv*256 + i*64)*8]);
                gload_lds16(Bt + (size_t)(n0 + row)*KDIM + k0 + cc, &Bs[(wv*256 + i*64)*8]);
            }
            __syncthreads();
#pragma unroll
            for (int kf = 0; kf < 2; ++kf) {
                bf16x8 af[4], bfr[4];
#pragma unroll
                for (int mt = 0; mt < 4; ++mt)
                    af[mt] = *(const bf16x8*)&As[(wm + mt*16 + lm)*BK + (((kf<<2)|quad) ^ sw)*8];
#pragma unroll
                for (int nt = 0; nt < 4; ++nt)
                    bfr[nt] = *(const bf16x8*)&Bs[(wn + nt*16 + lm)*BK + (((kf<<2)|quad) ^ sw)*8];
#pragma unroll
                for (int nt = 0; nt < 4; ++nt)
#pragma unroll
                    for (int mt = 0; mt < 4; ++mt)
                        acc[nt][mt] = __builtin_amdgcn_mfma_f32_16x16x32_bf16(bfr[nt], af[mt], acc[nt][mt], 0, 0, 0);
            }
        }
        __bf16* dst = (n0 < 1024) ? qF : kF;        // block-uniform
#pragma unroll
        for (int nt = 0; nt < 4; ++nt) {
            int f = n0 + wn + nt*16 + quad*4;
            float4 bs4 = *(const float4*)&bqk[f];
            int fl = f & 1023;
            int h  = fl >> 6;
            int ff = fl & 63;
            int fquad = (ff >> 3) & 3;
            int j0 = ff & 7;
            int kf = ff >> 5;
#pragma unroll
            for (int mt = 0; mt < 4; ++mt) {
                int m = m0 + wm + mt*16 + lm;
                int b = m >> 11, g = (m & 2047) >> 4;
                bf16x4 pk;
                pk[0] = (__bf16)(acc[nt][mt][0] + bs4.x);
                pk[1] = (__bf16)(acc[nt][mt][1] + bs4.y);
                pk[2] = (__bf16)(acc[nt][mt][2] + bs4.z);
                pk[3] = (__bf16)(acc[nt][mt][3] + bs4.w);
                size_t blk = (((size_t)(b*128 + g)*16 + h)*2 + kf);
                *(bf16x4*)&dst[blk*512 + (fquad*16 + lm)*8 + j0] = pk;
            }
        }
    } else {
        // ---------------- v path: acc[mt][nt] = C tiles -> vF frag-order ----------------
        for (int kt = 0; kt < KDIM/BK; ++kt) {
            const int k0 = kt * BK;
            __syncthreads();
#pragma unroll
            for (int i = 0; i < 4; ++i) {
                int slot = wv*256 + i*64 + ln;
                int row = slot >> 3, pq = slot & 7;
                int cc = (pq ^ (row & 7)) * 8;
                gload_lds16(A  + (size_t)(m0 + row)*KDIM + k0 + cc, &As[(wv*256 + i*64)*8]);
                gload_lds16(Bt + (size_t)(n0 + row)*KDIM + k0 + cc, &Bs[(wv*256 + i*64)*8]);
            }
            __syncthreads();
#pragma unroll
            for (int kf = 0; kf < 2; ++kf) {
                bf16x8 af[4], bfr[4];
#pragma unroll
                for (int mt = 0; mt < 4; ++mt)
                    af[mt] = *(const bf16x8*)&As[(wm + mt*16 + lm)*BK + (((kf<<2)|quad) ^ sw)*8];
#pragma unroll
                for (int nt = 0; nt < 4; ++nt)
                    bfr[nt] = *(const bf16x8*)&Bs[(wn + nt*16 + lm)*BK + (((kf<<2)|quad) ^ sw)*8];
#pragma unroll
                for (int mt = 0; mt < 4; ++mt)
#pragma unroll
                    for (int nt = 0; nt < 4; ++nt)
                        acc[mt][nt] = __builtin_amdgcn_mfma_f32_16x16x32_bf16(af[mt], bfr[nt], acc[mt][nt], 0, 0, 0);
            }
        }
#pragma unroll
        for (int mt = 0; mt < 4; ++mt) {
            int s4 = m0 + wm + mt*16 + quad*4;
            int b   = s4 >> 11;
            int kvt = (s4 & 2047) >> 6;
            int kv  = s4 & 63;
            int kf  = kv >> 5;
            int qv  = (kv >> 3) & 3;
            int j0  = kv & 7;
#pragma unroll
            for (int nt = 0; nt < 4; ++nt) {
                int cv = n0 + wn + nt*16 + lm - 2048;
                int h = cv >> 6, dv = cv & 63, nb = dv >> 4;
                float bs = bv[cv];
                bf16x4 pk;
#pragma unroll
                for (int r = 0; r < 4; ++r) pk[r] = (__bf16)(acc[mt][nt][r] + bs);
                size_t blk = (((size_t)((b*16 + h)*32 + kvt)*4 + nb)*2 + kf);
                *(bf16x4*)&vF[blk*512 + (qv*16 + lm)*8 + j0] = pk;
            }
        }
    }
}

// ---------------------------------------------------------------- flash attention v21 (unchanged)
// Banked-best structure (v18=142.8us; v21=145.1 same within noise): 8-wave/512-thread
// blocks, 16 q-rows/wave, KVBLK=128 (17 steps/CU pairwise-balanced), one-tile PV pipeline
// (PV(st-1) at barrier-exit overlaps QK(st)), register-resident P via permlane
// quad-exchange, fast_exp2. LDS 64KB: Ks[2][16KB]+Vs[2][16KB].
// kv-split refuted (v19/v20: 152-153); q-widening refuted (v15: occupancy loss).

__global__ __launch_bounds__(512, 4) void attn_kernel(const __bf16* __restrict__ qF,
                                                      const __bf16* __restrict__ kF,
                                                      const __bf16* __restrict__ vF,
                                                      float* __restrict__ out) {
    const int bh = blockIdx.x;
    const int b = bh >> 4, h = bh & 15;
    const int tyr = blockIdx.y;                     // 0..15
    const int ty = (tyr < 8) ? (15 - tyr) : (tyr - 8);  // heavy-first + pairwise balanced
    const int qb = ty * 128;
    const int tid = threadIdx.x, wv = tid >> 6, ln = tid & 63;
    const int quad = ln >> 4, lm = ln & 15;
    const int q0w = qb + wv*16;                     // this wave's 16 q-rows
    const int qg = q0w + lm;                        // this lane's q row

    __shared__ alignas(16) __bf16 Ks[2][16*512];    // 32KB: [buf][slot nt*2+kf][frag]
    __shared__ alignas(16) __bf16 Vs[2][16*512];    // 32KB: [buf][slot kvt*8+nb*2+kf][frag]

    // staging: each of 8 waves stages 2 K slots and 2 V slots per step (split issue)
    auto issueK = [&](int st, int buf) {
#pragma unroll
        for (int i = 0; i < 2; ++i) {
            const int j = wv*2 + i;                 // 0..15
            const int nt = j >> 1, kf = j & 1;
            const __bf16* gk = kF + ((((size_t)b*128 + st*8 + nt)*16 + h)*2 + kf)*512 + (size_t)ln*8;
            gload_lds16(gk, &Ks[buf][j*512]);
        }
    };
    auto issueV = [&](int st, int buf) {
#pragma unroll
        for (int i = 0; i < 2; ++i) {
            const int j = wv*2 + i;                 // 0..15
            const int kvt = j >> 3, nb = (j >> 1) & 3, kf = j & 1;
            const __bf16* gv = vF + ((((size_t)bh*32 + st*2 + kvt)*4 + nb)*2 + kf)*512 + (size_t)ln*8;
            gload_lds16(gv, &Vs[buf][j*512]);
        }
    };

    // Q fragments, pre-scaled by 0.125*log2(e) so P = exp2(S)
    const float qscale = 0.125f * 1.44269504088896f;
    bf16x8 qf[2];
#pragma unroll
    for (int kf = 0; kf < 2; ++kf) {
        bf16x8 t = *(const bf16x8*)&qF[((((size_t)b*128 + (q0w >> 4))*16 + h)*2 + kf)*512 + ln*8];
#pragma unroll
        for (int j = 0; j < 8; ++j) t[j] = (__bf16)((float)t[j] * qscale);
        qf[kf] = t;
    }
    bf16x8 ones;
#pragma unroll
    for (int j = 0; j < 8; ++j) ones[j] = (__bf16)1.0f;

    f32x4 o[4] = {};                                // O^T: (dv = nb*16+quad*4+r, q = lm)
    f32x4 o5 = {};                                  // l accumulator: every reg = l(q=lm)
    bf16x8 pf[4];                                   // loop-carried P fragments (tile st)
    const int nsteps = ty + 1;                      // 128-kv tiles

    // QK + softmax of tile (cur buffer), kv0 base, optional diagonal mask -> pf
    auto qk_sm = [&](int cur, int kv0, bool domask) {
        f32x4 s[8] = {};
        __builtin_amdgcn_s_setprio(1);
#pragma unroll
        for (int nt = 0; nt < 8; ++nt) {
            bf16x8 k0 = *(const bf16x8*)&Ks[cur][(nt*2 + 0)*512 + ln*8];
            bf16x8 k1 = *(const bf16x8*)&Ks[cur][(nt*2 + 1)*512 + ln*8];
            s[nt] = __builtin_amdgcn_mfma_f32_16x16x32_bf16(k0, qf[0], s[nt], 0, 0, 0);
            s[nt] = __builtin_amdgcn_mfma_f32_16x16x32_bf16(k1, qf[1], s[nt], 0, 0, 0);
        }
        __builtin_amdgcn_s_setprio(0);
        if (domask) {                               // diagonal step only; exp2(-1e9)=0
#pragma unroll
            for (int nt = 0; nt < 8; ++nt)
#pragma unroll
                for (int r = 0; r < 4; ++r) {
                    int kvg = kv0 + nt*16 + quad*4 + r;
                    if (kvg > qg) s[nt][r] = -1e9f;
                }
        }
        // per 64-kv group: exp2 + pack to bf16 dwords, then quad-exchange (register-only)
#pragma unroll
        for (int g = 0; g < 2; ++g) {
            unsigned d4[4][2];                      // d4[nt4][p] = (P[...,2p], P[...,2p+1])
#pragma unroll
            for (int nt4 = 0; nt4 < 4; ++nt4)
#pragma unroll
                for (int p = 0; p < 2; ++p) {
                    bf16x2 t;
                    t[0] = (__bf16)fast_exp2(s[g*4 + nt4][2*p]);
                    t[1] = (__bf16)fast_exp2(s[g*4 + nt4][2*p + 1]);
                    d4[nt4][p] = __builtin_bit_cast(unsigned, t);
                }
#pragma unroll
            for (int kfl = 0; kfl < 2; ++kfl) {
                unsigned w[4];
#pragma unroll
                for (int p = 0; p < 2; ++p) {
                    unsigned r0 = d4[kfl*2 + 0][p];
                    unsigned r1 = d4[kfl*2 + 1][p];
                    asm volatile("v_permlane32_swap_b32 %0, %1" : "+v"(r0), "+v"(r1));
                    asm volatile("v_permlane16_swap_b32 %0, %1" : "+v"(r0), "+v"(r1));
                    w[p]     = r0;
                    w[2 + p] = r1;
                }
                union { unsigned u[4]; bf16x8 v; } cvt;
                cvt.u[0] = w[0]; cvt.u[1] = w[1]; cvt.u[2] = w[2]; cvt.u[3] = w[3];
                pf[g*2 + kfl] = cvt.v;
            }
        }
    };

    // PV of the tile whose V sits in Vs[vb], P in pf
    auto pv = [&](int vb) {
        __builtin_amdgcn_s_setprio(1);
#pragma unroll
        for (int nb = 0; nb < 4; ++nb)
#pragma unroll
            for (int kfp = 0; kfp < 4; ++kfp) {
                bf16x8 vf = *(const bf16x8*)&Vs[vb][((kfp >> 1)*8 + nb*2 + (kfp & 1))*512 + ln*8];
                o[nb] = __builtin_amdgcn_mfma_f32_16x16x32_bf16(vf, pf[kfp], o[nb], 0, 0, 0);
            }
#pragma unroll
        for (int kfp = 0; kfp < 4; ++kfp)
            o5 = __builtin_amdgcn_mfma_f32_16x16x32_bf16(ones, pf[kfp], o5, 0, 0, 0);
        __builtin_amdgcn_s_setprio(0);
    };

    // ---- pipelined main loop (PV of tile st-1 overlaps QK of tile st)
    issueK(0, 0);
    __syncthreads();                                // drains K[0]
    issueV(0, 0);                                   // V first: consumed before K next step
    if (nsteps > 1) issueK(1, 1);
    qk_sm(0, 0, nsteps == 1);                       // -> pf of tile 0

    for (int st = 1; st < nsteps; ++st) {
        const int cur = st & 1;
        __syncthreads();                            // drains K[st] and V[st-1]
        issueV(st, cur);                            // V first (FIFO order = consumption order)
        if (st + 1 < nsteps) issueK(st + 1, cur ^ 1);
        pv(cur ^ 1);                                // PV of tile st-1 (operands ready now)
        qk_sm(cur, st * 128, st == nsteps - 1);     // -> pf of tile st
    }

    __syncthreads();                                // drains V[nsteps-1]
    pv((nsteps - 1) & 1);                           // drain pipeline

    // ---- epilogue: every lane holds l(q=lm) in o5
    const float invl = 1.0f / o5[0];
    float* orow = out + (size_t)(b*SEQ + q0w + lm)*DIM + h*64;
#pragma unroll
    for (int nb = 0; nb < 4; ++nb) {
        float4 vres;
        vres.x = o[nb][0] * invl;
        vres.y = o[nb][1] * invl;
        vres.z = o[nb][2] * invl;
        vres.w = o[nb][3] * invl;
        *(float4*)&orow[nb*16 + quad*4] = vres;
    }
}

// ---------------------------------------------------------------- launcher
extern "C" void kernel_launch(void* const* d_in, const int* in_sizes, int n_in,
                              void* d_out, int out_size, void* d_ws, size_t ws_size,
                              hipStream_t stream) {
    const float* x   = (const float*)d_in[0];
    const float* Wqk = (const float*)d_in[1];
    const float* bqk = (const float*)d_in[2];
    const float* Wv  = (const float*)d_in[3];
    const float* bv  = (const float*)d_in[4];
    float* out = (float*)d_out;

    char* ws = (char*)d_ws;
    const size_t SZ_XB = (size_t)MROWS*KDIM*2;    // 8 MB
    const size_t SZ_WT = (size_t)NTOT*KDIM*2;     // 6 MB
    const size_t SZ_F  = (size_t)MROWS*1024*2;    // 8 MB per frag buffer
    __bf16* xb = (__bf16*)(ws);
    __bf16* Wt = (__bf16*)(ws + SZ_XB);
    __bf16* qF = (__bf16*)(ws + SZ_XB + SZ_WT);
    __bf16* kF = (__bf16*)(ws + SZ_XB + SZ_WT + SZ_F);
    __bf16* vF = (__bf16*)(ws + SZ_XB + SZ_WT + 2*SZ_F);

    prep_kernel    <<<4096 + 768, 256, 0, stream>>>(x, Wqk, Wv, xb, Wt);
    gemm_qkv_kernel<<<dim3(NTOT/BN, MROWS/BM), 256, 0, stream>>>(xb, Wt, bqk, bv, qF, kF, vF);
    attn_kernel    <<<dim3(32, 16), 512, 0, stream>>>(qF, kF, vF, out);
}

// Round 13
// 139.097 us; speedup vs baseline: 1.1028x; 1.0141x over previous
//
#include <hip/hip_runtime.h>
#include <hip/hip_bf16.h>
#include <math.h>

// Problem constants
#define BATCH 2
#define SEQ   2048
#define DIM   1024
#define HEADS 16
#define DH    64
#define MROWS (BATCH*SEQ)      // 4096
#define NTOT  3072             // gemm output cols: q(1024) | k(1024) | v(1024)
#define KDIM  1024

typedef float f32x4 __attribute__((ext_vector_type(4)));
typedef __bf16 bf16x8 __attribute__((ext_vector_type(8)));
typedef __bf16 bf16x4 __attribute__((ext_vector_type(4)));
typedef __bf16 bf16x2 __attribute__((ext_vector_type(2)));

// Fragment-order buffers (1KB block = 64 lanes x 16B chunk, lane ln = featquad*16 + (token&15)):
//  qF/kF: block index ((b*128 + g)*16 + h)*2 + kf      g = token-group (16 tokens)
//  vF   : block index ((bh*32 + kvt)*4 + nb)*2 + kf    kvt = kv/64, dv-group nb
// One 1KB block == one wave64 global_load_lds (base + ln*16B) == one b128 LDS frag read.

__device__ __forceinline__ void gload_lds16(const void* g, void* l) {
    __builtin_amdgcn_global_load_lds((__attribute__((address_space(1))) void*)g,
                                     (__attribute__((address_space(3))) void*)l,
                                     16, 0, 0);
}

// raw v_exp_f32: skips OCML exp2f's denormal-fixup sequence. Validated v15/v16/v17b/v18.
__device__ __forceinline__ float fast_exp2(float x) {
    float r;
    asm("v_exp_f32 %0, %1" : "=v"(r) : "v"(x));
    return r;
}

// ---------------------------------------------- prep: cast x -> bf16  +  transpose W -> Wt
// v23: x-cast widened to bf16x8 (2x float4 in, 16B out per lane; 2048 blocks, was 4096) --
// halves instruction count + launch width on this pure-BW pass (G13 sweet spot).
// Transpose phase unchanged from v22 (float4 loads, bf16x4 stores, 65-pad LDS).
__global__ void prep_kernel(const float* __restrict__ x,
                            const float* __restrict__ Wqk, const float* __restrict__ Wv,
                            __bf16* __restrict__ xb, __bf16* __restrict__ Wt) {
    __shared__ float T[64*65];
    const int bx = blockIdx.x;
    const int tid = threadIdx.x;
    if (bx < 2048) {
        int i = bx * 256 + tid;                   // 512K iterations x 8 floats = 4M exactly
        float4 f0 = ((const float4*)x)[i*2 + 0];
        float4 f1 = ((const float4*)x)[i*2 + 1];
        bf16x8 o;
        o[0] = (__bf16)f0.x; o[1] = (__bf16)f0.y; o[2] = (__bf16)f0.z; o[3] = (__bf16)f0.w;
        o[4] = (__bf16)f1.x; o[5] = (__bf16)f1.y; o[6] = (__bf16)f1.z; o[7] = (__bf16)f1.w;
        ((bf16x8*)xb)[i] = o;
    } else {
        const int t = bx - 2048;                  // 0..767
        const int n0 = (t % 48) * 64;
        const int k0 = (t / 48) * 64;
        const bool isV = (n0 >= 2048);            // block-uniform
        const float* src = isV ? Wv : Wqk;
        const int stride = isV ? 1024 : 2048;
        const int ncol = isV ? (n0 - 2048) : n0;
#pragma unroll
        for (int i = 0; i < 4; ++i) {
            int idx = i*256 + tid;                // 0..1023
            int kk = idx >> 4;                    // 0..63
            int nn = (idx & 15) * 4;              // 0..60, float4-aligned
            float4 v = *(const float4*)&src[(size_t)(k0+kk)*stride + ncol + nn];
            T[kk*65 + nn + 0] = v.x;
            T[kk*65 + nn + 1] = v.y;
            T[kk*65 + nn + 2] = v.z;
            T[kk*65 + nn + 3] = v.w;
        }
        __syncthreads();
#pragma unroll
        for (int i = 0; i < 4; ++i) {
            int idx = i*256 + tid;
            int nn = idx >> 4;                    // 0..63
            int kk = (idx & 15) * 4;              // 0..60
            bf16x4 o;
            o[0] = (__bf16)T[(kk+0)*65 + nn];
            o[1] = (__bf16)T[(kk+1)*65 + nn];
            o[2] = (__bf16)T[(kk+2)*65 + nn];
            o[3] = (__bf16)T[(kk+3)*65 + nn];
            *(bf16x4*)&Wt[(size_t)(n0+nn)*KDIM + k0 + kk] = o;
        }
    }
}

// ---------------------------------------------------------------- GEMM v7: + XCD swizzle
#define BM 128
#define BN 128
#define BK 64

__global__ __launch_bounds__(256) void gemm_qkv_kernel(const __bf16* __restrict__ A,
                                                       const __bf16* __restrict__ Bt,
                                                       const float* __restrict__ bqk,
                                                       const float* __restrict__ bv,
                                                       __bf16* __restrict__ qF,
                                                       __bf16* __restrict__ kF,
                                                       __bf16* __restrict__ vF) {
    __shared__ alignas(16) __bf16 As[BM*BK];
    __shared__ alignas(16) __bf16 Bs[BN*BK];
    const int tid = threadIdx.x;
    const int wv = tid >> 6, ln = tid & 63;
    const int quad = ln >> 4, lm = ln & 15;
    // XCD-aware swizzle (T1): 768 blocks = 8 XCDs x 96 (bijective, 768%8==0). Each XCD
    // owns 3 B-panels x all 32 M-rows -> its Wt working set (0.75MB) is L2-resident
    // instead of thrashing across 8 incoherent per-XCD L2s. Perf-only remap.
    const int L = blockIdx.y * 24 + blockIdx.x;   // dispatch-linear (x fastest)
    const int xcd = L & 7, p = L >> 3;            // p in 0..95
    const int m0 = (p & 31) * BM;
    const int n0 = (3*xcd + (p >> 5)) * BN;
    const int wm = (wv >> 1) * 64, wn = (wv & 1) * 64;
    const int sw = lm & 7;

    f32x4 acc[4][4] = {};

    if (n0 < 2048) {
        // ---------------- q/k path: acc[nt][mt] = C^T tiles ----------------
        for (int kt = 0; kt < KDIM/BK; ++kt) {
            const int k0 = kt * BK;
            __syncthreads();
#pragma unroll
            for (int i = 0; i < 4; ++i) {
                int slot = wv*256 + i*64 + ln;
                int row = slot >> 3, pq = slot & 7;
                int cc = (pq ^ (row & 7)) * 8;
                gload_lds16(A  + (size_t)(m0 + row)*KDIM + k0 + cc, &As[(wv*256 + i*64)*8]);
                gload_lds16(Bt + (size_t)(n0 + row)*KDIM + k0 + cc, &Bs[(wv*256 + i*64)*8]);
            }
            __syncthreads();
#pragma unroll
            for (int kf = 0; kf < 2; ++kf) {
                bf16x8 af[4], bfr[4];
#pragma unroll
                for (int mt = 0; mt < 4; ++mt)
                    af[mt] = *(const bf16x8*)&As[(wm + mt*16 + lm)*BK + (((kf<<2)|quad) ^ sw)*8];
#pragma unroll
                for (int nt = 0; nt < 4; ++nt)
                    bfr[nt] = *(const bf16x8*)&Bs[(wn + nt*16 + lm)*BK + (((kf<<2)|quad) ^ sw)*8];
#pragma unroll
                for (int nt = 0; nt < 4; ++nt)
#pragma unroll
                    for (int mt = 0; mt < 4; ++mt)
                        acc[nt][mt] = __builtin_amdgcn_mfma_f32_16x16x32_bf16(bfr[nt], af[mt], acc[nt][mt], 0, 0, 0);
            }
        }
        __bf16* dst = (n0 < 1024) ? qF : kF;        // block-uniform
#pragma unroll
        for (int nt = 0; nt < 4; ++nt) {
            int f = n0 + wn + nt*16 + quad*4;
            float4 bs4 = *(const float4*)&bqk[f];
            int fl = f & 1023;
            int h  = fl >> 6;
            int ff = fl & 63;
            int fquad = (ff >> 3) & 3;
            int j0 = ff & 7;
            int kf = ff >> 5;
#pragma unroll
            for (int mt = 0; mt < 4; ++mt) {
                int m = m0 + wm + mt*16 + lm;
                int b = m >> 11, g = (m & 2047) >> 4;
                bf16x4 pk;
                pk[0] = (__bf16)(acc[nt][mt][0] + bs4.x);
                pk[1] = (__bf16)(acc[nt][mt][1] + bs4.y);
                pk[2] = (__bf16)(acc[nt][mt][2] + bs4.z);
                pk[3] = (__bf16)(acc[nt][mt][3] + bs4.w);
                size_t blk = (((size_t)(b*128 + g)*16 + h)*2 + kf);
                *(bf16x4*)&dst[blk*512 + (fquad*16 + lm)*8 + j0] = pk;
            }
        }
    } else {
        // ---------------- v path: acc[mt][nt] = C tiles -> vF frag-order ----------------
        for (int kt = 0; kt < KDIM/BK; ++kt) {
            const int k0 = kt * BK;
            __syncthreads();
#pragma unroll
            for (int i = 0; i < 4; ++i) {
                int slot = wv*256 + i*64 + ln;
                int row = slot >> 3, pq = slot & 7;
                int cc = (pq ^ (row & 7)) * 8;
                gload_lds16(A  + (size_t)(m0 + row)*KDIM + k0 + cc, &As[(wv*256 + i*64)*8]);
                gload_lds16(Bt + (size_t)(n0 + row)*KDIM + k0 + cc, &Bs[(wv*256 + i*64)*8]);
            }
            __syncthreads();
#pragma unroll
            for (int kf = 0; kf < 2; ++kf) {
                bf16x8 af[4], bfr[4];
#pragma unroll
                for (int mt = 0; mt < 4; ++mt)
                    af[mt] = *(const bf16x8*)&As[(wm + mt*16 + lm)*BK + (((kf<<2)|quad) ^ sw)*8];
#pragma unroll
                for (int nt = 0; nt < 4; ++nt)
                    bfr[nt] = *(const bf16x8*)&Bs[(wn + nt*16 + lm)*BK + (((kf<<2)|quad) ^ sw)*8];
#pragma unroll
                for (int mt = 0; mt < 4; ++mt)
#pragma unroll
                    for (int nt = 0; nt < 4; ++nt)
                        acc[mt][nt] = __builtin_amdgcn_mfma_f32_16x16x32_bf16(af[mt], bfr[nt], acc[mt][nt], 0, 0, 0);
            }
        }
#pragma unroll
        for (int mt = 0; mt < 4; ++mt) {
            int s4 = m0 + wm + mt*16 + quad*4;
            int b   = s4 >> 11;
            int kvt = (s4 & 2047) >> 6;
            int kv  = s4 & 63;
            int kf  = kv >> 5;
            int qv  = (kv >> 3) & 3;
            int j0  = kv & 7;
#pragma unroll
            for (int nt = 0; nt < 4; ++nt) {
                int cv = n0 + wn + nt*16 + lm - 2048;
                int h = cv >> 6, dv = cv & 63, nb = dv >> 4;
                float bs = bv[cv];
                bf16x4 pk;
#pragma unroll
                for (int r = 0; r < 4; ++r) pk[r] = (__bf16)(acc[mt][nt][r] + bs);
                size_t blk = (((size_t)((b*16 + h)*32 + kvt)*4 + nb)*2 + kf);
                *(bf16x4*)&vF[blk*512 + (qv*16 + lm)*8 + j0] = pk;
            }
        }
    }
}

// ---------------------------------------------------------------- flash attention v21 (unchanged)
// Banked-best structure (v18=142.8, v22=141.1): 8-wave/512-thread blocks, 16 q-rows/wave,
// KVBLK=128 (17 steps/CU pairwise-balanced), one-tile PV pipeline (PV(st-1) at
// barrier-exit overlaps QK(st)), register-resident P via permlane quad-exchange,
// fast_exp2. LDS 64KB: Ks[2][16KB]+Vs[2][16KB].
// Refuted: kv-split (v19/v20 +10us, spill-safe variant too -> serial-chain-bound, not
// LDS-BW); q-widening (v15, occupancy); one-tile hoisted-operand pipeline (v14, spill).

__global__ __launch_bounds__(512, 4) void attn_kernel(const __bf16* __restrict__ qF,
                                                      const __bf16* __restrict__ kF,
                                                      const __bf16* __restrict__ vF,
                                                      float* __restrict__ out) {
    const int bh = blockIdx.x;
    const int b = bh >> 4, h = bh & 15;
    const int tyr = blockIdx.y;                     // 0..15
    const int ty = (tyr < 8) ? (15 - tyr) : (tyr - 8);  // heavy-first + pairwise balanced
    const int qb = ty * 128;
    const int tid = threadIdx.x, wv = tid >> 6, ln = tid & 63;
    const int quad = ln >> 4, lm = ln & 15;
    const int q0w = qb + wv*16;                     // this wave's 16 q-rows
    const int qg = q0w + lm;                        // this lane's q row

    __shared__ alignas(16) __bf16 Ks[2][16*512];    // 32KB: [buf][slot nt*2+kf][frag]
    __shared__ alignas(16) __bf16 Vs[2][16*512];    // 32KB: [buf][slot kvt*8+nb*2+kf][frag]

    // staging: each of 8 waves stages 2 K slots and 2 V slots per step (split issue)
    auto issueK = [&](int st, int buf) {
#pragma unroll
        for (int i = 0; i < 2; ++i) {
            const int j = wv*2 + i;                 // 0..15
            const int nt = j >> 1, kf = j & 1;
            const __bf16* gk = kF + ((((size_t)b*128 + st*8 + nt)*16 + h)*2 + kf)*512 + (size_t)ln*8;
            gload_lds16(gk, &Ks[buf][j*512]);
        }
    };
    auto issueV = [&](int st, int buf) {
#pragma unroll
        for (int i = 0; i < 2; ++i) {
            const int j = wv*2 + i;                 // 0..15
            const int kvt = j >> 3, nb = (j >> 1) & 3, kf = j & 1;
            const __bf16* gv = vF + ((((size_t)bh*32 + st*2 + kvt)*4 + nb)*2 + kf)*512 + (size_t)ln*8;
            gload_lds16(gv, &Vs[buf][j*512]);
        }
    };

    // Q fragments, pre-scaled by 0.125*log2(e) so P = exp2(S)
    const float qscale = 0.125f * 1.44269504088896f;
    bf16x8 qf[2];
#pragma unroll
    for (int kf = 0; kf < 2; ++kf) {
        bf16x8 t = *(const bf16x8*)&qF[((((size_t)b*128 + (q0w >> 4))*16 + h)*2 + kf)*512 + ln*8];
#pragma unroll
        for (int j = 0; j < 8; ++j) t[j] = (__bf16)((float)t[j] * qscale);
        qf[kf] = t;
    }
    bf16x8 ones;
#pragma unroll
    for (int j = 0; j < 8; ++j) ones[j] = (__bf16)1.0f;

    f32x4 o[4] = {};                                // O^T: (dv = nb*16+quad*4+r, q = lm)
    f32x4 o5 = {};                                  // l accumulator: every reg = l(q=lm)
    bf16x8 pf[4];                                   // loop-carried P fragments (tile st)
    const int nsteps = ty + 1;                      // 128-kv tiles

    // QK + softmax of tile (cur buffer), kv0 base, optional diagonal mask -> pf
    auto qk_sm = [&](int cur, int kv0, bool domask) {
        f32x4 s[8] = {};
        __builtin_amdgcn_s_setprio(1);
#pragma unroll
        for (int nt = 0; nt < 8; ++nt) {
            bf16x8 k0 = *(const bf16x8*)&Ks[cur][(nt*2 + 0)*512 + ln*8];
            bf16x8 k1 = *(const bf16x8*)&Ks[cur][(nt*2 + 1)*512 + ln*8];
            s[nt] = __builtin_amdgcn_mfma_f32_16x16x32_bf16(k0, qf[0], s[nt], 0, 0, 0);
            s[nt] = __builtin_amdgcn_mfma_f32_16x16x32_bf16(k1, qf[1], s[nt], 0, 0, 0);
        }
        __builtin_amdgcn_s_setprio(0);
        if (domask) {                               // diagonal step only; exp2(-1e9)=0
#pragma unroll
            for (int nt = 0; nt < 8; ++nt)
#pragma unroll
                for (int r = 0; r < 4; ++r) {
                    int kvg = kv0 + nt*16 + quad*4 + r;
                    if (kvg > qg) s[nt][r] = -1e9f;
                }
        }
        // per 64-kv group: exp2 + pack to bf16 dwords, then quad-exchange (register-only)
#pragma unroll
        for (int g = 0; g < 2; ++g) {
            unsigned d4[4][2];                      // d4[nt4][p] = (P[...,2p], P[...,2p+1])
#pragma unroll
            for (int nt4 = 0; nt4 < 4; ++nt4)
#pragma unroll
                for (int p = 0; p < 2; ++p) {
                    bf16x2 t;
                    t[0] = (__bf16)fast_exp2(s[g*4 + nt4][2*p]);
                    t[1] = (__bf16)fast_exp2(s[g*4 + nt4][2*p + 1]);
                    d4[nt4][p] = __builtin_bit_cast(unsigned, t);
                }
#pragma unroll
            for (int kfl = 0; kfl < 2; ++kfl) {
                unsigned w[4];
#pragma unroll
                for (int p = 0; p < 2; ++p) {
                    unsigned r0 = d4[kfl*2 + 0][p];
                    unsigned r1 = d4[kfl*2 + 1][p];
                    asm volatile("v_permlane32_swap_b32 %0, %1" : "+v"(r0), "+v"(r1));
                    asm volatile("v_permlane16_swap_b32 %0, %1" : "+v"(r0), "+v"(r1));
                    w[p]     = r0;
                    w[2 + p] = r1;
                }
                union { unsigned u[4]; bf16x8 v; } cvt;
                cvt.u[0] = w[0]; cvt.u[1] = w[1]; cvt.u[2] = w[2]; cvt.u[3] = w[3];
                pf[g*2 + kfl] = cvt.v;
            }
        }
    };

    // PV of the tile whose V sits in Vs[vb], P in pf
    auto pv = [&](int vb) {
        __builtin_amdgcn_s_setprio(1);
#pragma unroll
        for (int nb = 0; nb < 4; ++nb)
#pragma unroll
            for (int kfp = 0; kfp < 4; ++kfp) {
                bf16x8 vf = *(const bf16x8*)&Vs[vb][((kfp >> 1)*8 + nb*2 + (kfp & 1))*512 + ln*8];
                o[nb] = __builtin_amdgcn_mfma_f32_16x16x32_bf16(vf, pf[kfp], o[nb], 0, 0, 0);
            }
#pragma unroll
        for (int kfp = 0; kfp < 4; ++kfp)
            o5 = __builtin_amdgcn_mfma_f32_16x16x32_bf16(ones, pf[kfp], o5, 0, 0, 0);
        __builtin_amdgcn_s_setprio(0);
    };

    // ---- pipelined main loop (PV of tile st-1 overlaps QK of tile st)
    issueK(0, 0);
    __syncthreads();                                // drains K[0]
    issueV(0, 0);                                   // V first: consumed before K next step
    if (nsteps > 1) issueK(1, 1);
    qk_sm(0, 0, nsteps == 1);                       // -> pf of tile 0

    for (int st = 1; st < nsteps; ++st) {
        const int cur = st & 1;
        __syncthreads();                            // drains K[st] and V[st-1]
        issueV(st, cur);                            // V first (FIFO order = consumption order)
        if (st + 1 < nsteps) issueK(st + 1, cur ^ 1);
        pv(cur ^ 1);                                // PV of tile st-1 (operands ready now)
        qk_sm(cur, st * 128, st == nsteps - 1);     // -> pf of tile st
    }

    __syncthreads();                                // drains V[nsteps-1]
    pv((nsteps - 1) & 1);                           // drain pipeline

    // ---- epilogue: every lane holds l(q=lm) in o5
    const float invl = 1.0f / o5[0];
    float* orow = out + (size_t)(b*SEQ + q0w + lm)*DIM + h*64;
#pragma unroll
    for (int nb = 0; nb < 4; ++nb) {
        float4 vres;
        vres.x = o[nb][0] * invl;
        vres.y = o[nb][1] * invl;
        vres.z = o[nb][2] * invl;
        vres.w = o[nb][3] * invl;
        *(float4*)&orow[nb*16 + quad*4] = vres;
    }
}

// ---------------------------------------------------------------- launcher
extern "C" void kernel_launch(void* const* d_in, const int* in_sizes, int n_in,
                              void* d_out, int out_size, void* d_ws, size_t ws_size,
                              hipStream_t stream) {
    const float* x   = (const float*)d_in[0];
    const float* Wqk = (const float*)d_in[1];
    const float* bqk = (const float*)d_in[2];
    const float* Wv  = (const float*)d_in[3];
    const float* bv  = (const float*)d_in[4];
    float* out = (float*)d_out;

    char* ws = (char*)d_ws;
    const size_t SZ_XB = (size_t)MROWS*KDIM*2;    // 8 MB
    const size_t SZ_WT = (size_t)NTOT*KDIM*2;     // 6 MB
    const size_t SZ_F  = (size_t)MROWS*1024*2;    // 8 MB per frag buffer
    __bf16* xb = (__bf16*)(ws);
    __bf16* Wt = (__bf16*)(ws + SZ_XB);
    __bf16* qF = (__bf16*)(ws + SZ_XB + SZ_WT);
    __bf16* kF = (__bf16*)(ws + SZ_XB + SZ_WT + SZ_F);
    __bf16* vF = (__bf16*)(ws + SZ_XB + SZ_WT + 2*SZ_F);

    prep_kernel    <<<2048 + 768, 256, 0, stream>>>(x, Wqk, Wv, xb, Wt);
    gemm_qkv_kernel<<<dim3(NTOT/BN, MROWS/BM), 256, 0, stream>>>(xb, Wt, bqk, bv, qF, kF, vF);
    attn_kernel    <<<dim3(32, 16), 512, 0, stream>>>(qF, kF, vF, out);
}

// Round 14
// 138.434 us; speedup vs baseline: 1.1081x; 1.0048x over previous
//
#include <hip/hip_runtime.h>
#include <hip/hip_bf16.h>
#include <math.h>

// Problem constants
#define BATCH 2
#define SEQ   2048
#define DIM   1024
#define HEADS 16
#define DH    64
#define MROWS (BATCH*SEQ)      // 4096
#define NTOT  3072             // gemm output cols: q(1024) | k(1024) | v(1024)
#define KDIM  1024

typedef float f32x4 __attribute__((ext_vector_type(4)));
typedef __bf16 bf16x8 __attribute__((ext_vector_type(8)));
typedef __bf16 bf16x4 __attribute__((ext_vector_type(4)));
typedef __bf16 bf16x2 __attribute__((ext_vector_type(2)));

// Fragment-order buffers (1KB block = 64 lanes x 16B chunk, lane ln = featquad*16 + (token&15)):
//  qF/kF: block index ((b*128 + g)*16 + h)*2 + kf      g = token-group (16 tokens)
//  vF   : block index ((bh*32 + kvt)*4 + nb)*2 + kf    kvt = kv/64, dv-group nb
// One 1KB block == one wave64 global_load_lds (base + ln*16B) == one b128 LDS frag read.

__device__ __forceinline__ void gload_lds16(const void* g, void* l) {
    __builtin_amdgcn_global_load_lds((__attribute__((address_space(1))) void*)g,
                                     (__attribute__((address_space(3))) void*)l,
                                     16, 0, 0);
}

// raw v_exp_f32: skips OCML exp2f's denormal-fixup sequence. Validated v15/v16/v17b/v18.
__device__ __forceinline__ float fast_exp2(float x) {
    float r;
    asm("v_exp_f32 %0, %1" : "=v"(r) : "v"(x));
    return r;
}

// ---------------------------------------------- prep: cast x -> bf16  +  transpose W -> Wt
// v23 (frozen): x-cast bf16x8 (2048 blocks); transpose float4-in / bf16x4-out, 65-pad LDS.
__global__ void prep_kernel(const float* __restrict__ x,
                            const float* __restrict__ Wqk, const float* __restrict__ Wv,
                            __bf16* __restrict__ xb, __bf16* __restrict__ Wt) {
    __shared__ float T[64*65];
    const int bx = blockIdx.x;
    const int tid = threadIdx.x;
    if (bx < 2048) {
        int i = bx * 256 + tid;                   // 512K iterations x 8 floats = 4M exactly
        float4 f0 = ((const float4*)x)[i*2 + 0];
        float4 f1 = ((const float4*)x)[i*2 + 1];
        bf16x8 o;
        o[0] = (__bf16)f0.x; o[1] = (__bf16)f0.y; o[2] = (__bf16)f0.z; o[3] = (__bf16)f0.w;
        o[4] = (__bf16)f1.x; o[5] = (__bf16)f1.y; o[6] = (__bf16)f1.z; o[7] = (__bf16)f1.w;
        ((bf16x8*)xb)[i] = o;
    } else {
        const int t = bx - 2048;                  // 0..767
        const int n0 = (t % 48) * 64;
        const int k0 = (t / 48) * 64;
        const bool isV = (n0 >= 2048);            // block-uniform
        const float* src = isV ? Wv : Wqk;
        const int stride = isV ? 1024 : 2048;
        const int ncol = isV ? (n0 - 2048) : n0;
#pragma unroll
        for (int i = 0; i < 4; ++i) {
            int idx = i*256 + tid;                // 0..1023
            int kk = idx >> 4;                    // 0..63
            int nn = (idx & 15) * 4;              // 0..60, float4-aligned
            float4 v = *(const float4*)&src[(size_t)(k0+kk)*stride + ncol + nn];
            T[kk*65 + nn + 0] = v.x;
            T[kk*65 + nn + 1] = v.y;
            T[kk*65 + nn + 2] = v.z;
            T[kk*65 + nn + 3] = v.w;
        }
        __syncthreads();
#pragma unroll
        for (int i = 0; i < 4; ++i) {
            int idx = i*256 + tid;
            int nn = idx >> 4;                    // 0..63
            int kk = (idx & 15) * 4;              // 0..60
            bf16x4 o;
            o[0] = (__bf16)T[(kk+0)*65 + nn];
            o[1] = (__bf16)T[(kk+1)*65 + nn];
            o[2] = (__bf16)T[(kk+2)*65 + nn];
            o[3] = (__bf16)T[(kk+3)*65 + nn];
            *(bf16x4*)&Wt[(size_t)(n0+nn)*KDIM + k0 + kk] = o;
        }
    }
}

// ---------------------------------------------------------------- GEMM v8: 2D XCD patch
#define BM 128
#define BN 128
#define BK 64

__global__ __launch_bounds__(256) void gemm_qkv_kernel(const __bf16* __restrict__ A,
                                                       const __bf16* __restrict__ Bt,
                                                       const float* __restrict__ bqk,
                                                       const float* __restrict__ bv,
                                                       __bf16* __restrict__ qF,
                                                       __bf16* __restrict__ kF,
                                                       __bf16* __restrict__ vF) {
    __shared__ alignas(16) __bf16 As[BM*BK];
    __shared__ alignas(16) __bf16 Bs[BN*BK];
    const int tid = threadIdx.x;
    const int wv = tid >> 6, ln = tid & 63;
    const int quad = ln >> 4, lm = ln & 15;
    // v24: 2D XCD patch (was v22's 3n x 32m stripes). All 768 blocks are CO-RESIDENT
    // (3 blocks/CU), so scheduling order is irrelevant -- what matters is each XCD's
    // AGGREGATE working set. Stripes: B-set 0.75MB (L2 ok) but A-set 8MB > 4MB L2 ->
    // every A re-read (24x/panel) went to L3. Patch: 8 XCDs as 4(m) x 2(n), each owning
    // 8 m-panels x 12 n-panels = 96 blocks -> A-set 2MB + B-set 3MB ~= L2-resident.
    // Bijective: 768 = 8 x 96. Perf-only remap.
    const int L = blockIdx.y * 24 + blockIdx.x;   // dispatch-linear (x fastest)
    const int xcd = L & 7, p = L >> 3;            // p in 0..95
    const int mx = xcd & 3, ny = xcd >> 2;
    const int m0 = (mx*8 + (p & 7)) * BM;         // m-panel 0..31
    const int n0 = (ny*12 + (p >> 3)) * BN;       // n-panel 0..23
    const int wm = (wv >> 1) * 64, wn = (wv & 1) * 64;
    const int sw = lm & 7;

    f32x4 acc[4][4] = {};

    if (n0 < 2048) {
        // ---------------- q/k path: acc[nt][mt] = C^T tiles ----------------
        for (int kt = 0; kt < KDIM/BK; ++kt) {
            const int k0 = kt * BK;
            __syncthreads();
#pragma unroll
            for (int i = 0; i < 4; ++i) {
                int slot = wv*256 + i*64 + ln;
                int row = slot >> 3, pq = slot & 7;
                int cc = (pq ^ (row & 7)) * 8;
                gload_lds16(A  + (size_t)(m0 + row)*KDIM + k0 + cc, &As[(wv*256 + i*64)*8]);
                gload_lds16(Bt + (size_t)(n0 + row)*KDIM + k0 + cc, &Bs[(wv*256 + i*64)*8]);
            }
            __syncthreads();
#pragma unroll
            for (int kf = 0; kf < 2; ++kf) {
                bf16x8 af[4], bfr[4];
#pragma unroll
                for (int mt = 0; mt < 4; ++mt)
                    af[mt] = *(const bf16x8*)&As[(wm + mt*16 + lm)*BK + (((kf<<2)|quad) ^ sw)*8];
#pragma unroll
                for (int nt = 0; nt < 4; ++nt)
                    bfr[nt] = *(const bf16x8*)&Bs[(wn + nt*16 + lm)*BK + (((kf<<2)|quad) ^ sw)*8];
#pragma unroll
                for (int nt = 0; nt < 4; ++nt)
#pragma unroll
                    for (int mt = 0; mt < 4; ++mt)
                        acc[nt][mt] = __builtin_amdgcn_mfma_f32_16x16x32_bf16(bfr[nt], af[mt], acc[nt][mt], 0, 0, 0);
            }
        }
        __bf16* dst = (n0 < 1024) ? qF : kF;        // block-uniform
#pragma unroll
        for (int nt = 0; nt < 4; ++nt) {
            int f = n0 + wn + nt*16 + quad*4;
            float4 bs4 = *(const float4*)&bqk[f];
            int fl = f & 1023;
            int h  = fl >> 6;
            int ff = fl & 63;
            int fquad = (ff >> 3) & 3;
            int j0 = ff & 7;
            int kf = ff >> 5;
#pragma unroll
            for (int mt = 0; mt < 4; ++mt) {
                int m = m0 + wm + mt*16 + lm;
                int b = m >> 11, g = (m & 2047) >> 4;
                bf16x4 pk;
                pk[0] = (__bf16)(acc[nt][mt][0] + bs4.x);
                pk[1] = (__bf16)(acc[nt][mt][1] + bs4.y);
                pk[2] = (__bf16)(acc[nt][mt][2] + bs4.z);
                pk[3] = (__bf16)(acc[nt][mt][3] + bs4.w);
                size_t blk = (((size_t)(b*128 + g)*16 + h)*2 + kf);
                *(bf16x4*)&dst[blk*512 + (fquad*16 + lm)*8 + j0] = pk;
            }
        }
    } else {
        // ---------------- v path: acc[mt][nt] = C tiles -> vF frag-order ----------------
        for (int kt = 0; kt < KDIM/BK; ++kt) {
            const int k0 = kt * BK;
            __syncthreads();
#pragma unroll
            for (int i = 0; i < 4; ++i) {
                int slot = wv*256 + i*64 + ln;
                int row = slot >> 3, pq = slot & 7;
                int cc = (pq ^ (row & 7)) * 8;
                gload_lds16(A  + (size_t)(m0 + row)*KDIM + k0 + cc, &As[(wv*256 + i*64)*8]);
                gload_lds16(Bt + (size_t)(n0 + row)*KDIM + k0 + cc, &Bs[(wv*256 + i*64)*8]);
            }
            __syncthreads();
#pragma unroll
            for (int kf = 0; kf < 2; ++kf) {
                bf16x8 af[4], bfr[4];
#pragma unroll
                for (int mt = 0; mt < 4; ++mt)
                    af[mt] = *(const bf16x8*)&As[(wm + mt*16 + lm)*BK + (((kf<<2)|quad) ^ sw)*8];
#pragma unroll
                for (int nt = 0; nt < 4; ++nt)
                    bfr[nt] = *(const bf16x8*)&Bs[(wn + nt*16 + lm)*BK + (((kf<<2)|quad) ^ sw)*8];
#pragma unroll
                for (int mt = 0; mt < 4; ++mt)
#pragma unroll
                    for (int nt = 0; nt < 4; ++nt)
                        acc[mt][nt] = __builtin_amdgcn_mfma_f32_16x16x32_bf16(af[mt], bfr[nt], acc[mt][nt], 0, 0, 0);
            }
        }
#pragma unroll
        for (int mt = 0; mt < 4; ++mt) {
            int s4 = m0 + wm + mt*16 + quad*4;
            int b   = s4 >> 11;
            int kvt = (s4 & 2047) >> 6;
            int kv  = s4 & 63;
            int kf  = kv >> 5;
            int qv  = (kv >> 3) & 3;
            int j0  = kv & 7;
#pragma unroll
            for (int nt = 0; nt < 4; ++nt) {
                int cv = n0 + wn + nt*16 + lm - 2048;
                int h = cv >> 6, dv = cv & 63, nb = dv >> 4;
                float bs = bv[cv];
                bf16x4 pk;
#pragma unroll
                for (int r = 0; r < 4; ++r) pk[r] = (__bf16)(acc[mt][nt][r] + bs);
                size_t blk = (((size_t)((b*16 + h)*32 + kvt)*4 + nb)*2 + kf);
                *(bf16x4*)&vF[blk*512 + (qv*16 + lm)*8 + j0] = pk;
            }
        }
    }
}

// ---------------------------------------------------------------- flash attention v21 (frozen)
// Banked-best structure (v18=142.8, v22=141.1, v23=139.1): 8-wave/512-thread blocks,
// 16 q-rows/wave, KVBLK=128 (17 steps/CU pairwise-balanced), one-tile PV pipeline
// (PV(st-1) at barrier-exit overlaps QK(st)), register-resident P via permlane
// quad-exchange, fast_exp2. LDS 64KB: Ks[2][16KB]+Vs[2][16KB].
// Refuted: kv-split (v19/v20 +10us, spill-safe too -> serial-chain-bound, not LDS-BW);
// q-widening (v15, occupancy); one-tile hoisted-operand pipeline (v14, spill).

__global__ __launch_bounds__(512, 4) void attn_kernel(const __bf16* __restrict__ qF,
                                                      const __bf16* __restrict__ kF,
                                                      const __bf16* __restrict__ vF,
                                                      float* __restrict__ out) {
    const int bh = blockIdx.x;
    const int b = bh >> 4, h = bh & 15;
    const int tyr = blockIdx.y;                     // 0..15
    const int ty = (tyr < 8) ? (15 - tyr) : (tyr - 8);  // heavy-first + pairwise balanced
    const int qb = ty * 128;
    const int tid = threadIdx.x, wv = tid >> 6, ln = tid & 63;
    const int quad = ln >> 4, lm = ln & 15;
    const int q0w = qb + wv*16;                     // this wave's 16 q-rows
    const int qg = q0w + lm;                        // this lane's q row

    __shared__ alignas(16) __bf16 Ks[2][16*512];    // 32KB: [buf][slot nt*2+kf][frag]
    __shared__ alignas(16) __bf16 Vs[2][16*512];    // 32KB: [buf][slot kvt*8+nb*2+kf][frag]

    // staging: each of 8 waves stages 2 K slots and 2 V slots per step (split issue)
    auto issueK = [&](int st, int buf) {
#pragma unroll
        for (int i = 0; i < 2; ++i) {
            const int j = wv*2 + i;                 // 0..15
            const int nt = j >> 1, kf = j & 1;
            const __bf16* gk = kF + ((((size_t)b*128 + st*8 + nt)*16 + h)*2 + kf)*512 + (size_t)ln*8;
            gload_lds16(gk, &Ks[buf][j*512]);
        }
    };
    auto issueV = [&](int st, int buf) {
#pragma unroll
        for (int i = 0; i < 2; ++i) {
            const int j = wv*2 + i;                 // 0..15
            const int kvt = j >> 3, nb = (j >> 1) & 3, kf = j & 1;
            const __bf16* gv = vF + ((((size_t)bh*32 + st*2 + kvt)*4 + nb)*2 + kf)*512 + (size_t)ln*8;
            gload_lds16(gv, &Vs[buf][j*512]);
        }
    };

    // Q fragments, pre-scaled by 0.125*log2(e) so P = exp2(S)
    const float qscale = 0.125f * 1.44269504088896f;
    bf16x8 qf[2];
#pragma unroll
    for (int kf = 0; kf < 2; ++kf) {
        bf16x8 t = *(const bf16x8*)&qF[((((size_t)b*128 + (q0w >> 4))*16 + h)*2 + kf)*512 + ln*8];
#pragma unroll
        for (int j = 0; j < 8; ++j) t[j] = (__bf16)((float)t[j] * qscale);
        qf[kf] = t;
    }
    bf16x8 ones;
#pragma unroll
    for (int j = 0; j < 8; ++j) ones[j] = (__bf16)1.0f;

    f32x4 o[4] = {};                                // O^T: (dv = nb*16+quad*4+r, q = lm)
    f32x4 o5 = {};                                  // l accumulator: every reg = l(q=lm)
    bf16x8 pf[4];                                   // loop-carried P fragments (tile st)
    const int nsteps = ty + 1;                      // 128-kv tiles

    // QK + softmax of tile (cur buffer), kv0 base, optional diagonal mask -> pf
    auto qk_sm = [&](int cur, int kv0, bool domask) {
        f32x4 s[8] = {};
        __builtin_amdgcn_s_setprio(1);
#pragma unroll
        for (int nt = 0; nt < 8; ++nt) {
            bf16x8 k0 = *(const bf16x8*)&Ks[cur][(nt*2 + 0)*512 + ln*8];
            bf16x8 k1 = *(const bf16x8*)&Ks[cur][(nt*2 + 1)*512 + ln*8];
            s[nt] = __builtin_amdgcn_mfma_f32_16x16x32_bf16(k0, qf[0], s[nt], 0, 0, 0);
            s[nt] = __builtin_amdgcn_mfma_f32_16x16x32_bf16(k1, qf[1], s[nt], 0, 0, 0);
        }
        __builtin_amdgcn_s_setprio(0);
        if (domask) {                               // diagonal step only; exp2(-1e9)=0
#pragma unroll
            for (int nt = 0; nt < 8; ++nt)
#pragma unroll
                for (int r = 0; r < 4; ++r) {
                    int kvg = kv0 + nt*16 + quad*4 + r;
                    if (kvg > qg) s[nt][r] = -1e9f;
                }
        }
        // per 64-kv group: exp2 + pack to bf16 dwords, then quad-exchange (register-only)
#pragma unroll
        for (int g = 0; g < 2; ++g) {
            unsigned d4[4][2];                      // d4[nt4][p] = (P[...,2p], P[...,2p+1])
#pragma unroll
            for (int nt4 = 0; nt4 < 4; ++nt4)
#pragma unroll
                for (int p = 0; p < 2; ++p) {
                    bf16x2 t;
                    t[0] = (__bf16)fast_exp2(s[g*4 + nt4][2*p]);
                    t[1] = (__bf16)fast_exp2(s[g*4 + nt4][2*p + 1]);
                    d4[nt4][p] = __builtin_bit_cast(unsigned, t);
                }
#pragma unroll
            for (int kfl = 0; kfl < 2; ++kfl) {
                unsigned w[4];
#pragma unroll
                for (int p = 0; p < 2; ++p) {
                    unsigned r0 = d4[kfl*2 + 0][p];
                    unsigned r1 = d4[kfl*2 + 1][p];
                    asm volatile("v_permlane32_swap_b32 %0, %1" : "+v"(r0), "+v"(r1));
                    asm volatile("v_permlane16_swap_b32 %0, %1" : "+v"(r0), "+v"(r1));
                    w[p]     = r0;
                    w[2 + p] = r1;
                }
                union { unsigned u[4]; bf16x8 v; } cvt;
                cvt.u[0] = w[0]; cvt.u[1] = w[1]; cvt.u[2] = w[2]; cvt.u[3] = w[3];
                pf[g*2 + kfl] = cvt.v;
            }
        }
    };

    // PV of the tile whose V sits in Vs[vb], P in pf
    auto pv = [&](int vb) {
        __builtin_amdgcn_s_setprio(1);
#pragma unroll
        for (int nb = 0; nb < 4; ++nb)
#pragma unroll
            for (int kfp = 0; kfp < 4; ++kfp) {
                bf16x8 vf = *(const bf16x8*)&Vs[vb][((kfp >> 1)*8 + nb*2 + (kfp & 1))*512 + ln*8];
                o[nb] = __builtin_amdgcn_mfma_f32_16x16x32_bf16(vf, pf[kfp], o[nb], 0, 0, 0);
            }
#pragma unroll
        for (int kfp = 0; kfp < 4; ++kfp)
            o5 = __builtin_amdgcn_mfma_f32_16x16x32_bf16(ones, pf[kfp], o5, 0, 0, 0);
        __builtin_amdgcn_s_setprio(0);
    };

    // ---- pipelined main loop (PV of tile st-1 overlaps QK of tile st)
    issueK(0, 0);
    __syncthreads();                                // drains K[0]
    issueV(0, 0);                                   // V first: consumed before K next step
    if (nsteps > 1) issueK(1, 1);
    qk_sm(0, 0, nsteps == 1);                       // -> pf of tile 0

    for (int st = 1; st < nsteps; ++st) {
        const int cur = st & 1;
        __syncthreads();                            // drains K[st] and V[st-1]
        issueV(st, cur);                            // V first (FIFO order = consumption order)
        if (st + 1 < nsteps) issueK(st + 1, cur ^ 1);
        pv(cur ^ 1);                                // PV of tile st-1 (operands ready now)
        qk_sm(cur, st * 128, st == nsteps - 1);     // -> pf of tile st
    }

    __syncthreads();                                // drains V[nsteps-1]
    pv((nsteps - 1) & 1);                           // drain pipeline

    // ---- epilogue: every lane holds l(q=lm) in o5
    const float invl = 1.0f / o5[0];
    float* orow = out + (size_t)(b*SEQ + q0w + lm)*DIM + h*64;
#pragma unroll
    for (int nb = 0; nb < 4; ++nb) {
        float4 vres;
        vres.x = o[nb][0] * invl;
        vres.y = o[nb][1] * invl;
        vres.z = o[nb][2] * invl;
        vres.w = o[nb][3] * invl;
        *(float4*)&orow[nb*16 + quad*4] = vres;
    }
}

// ---------------------------------------------------------------- launcher
extern "C" void kernel_launch(void* const* d_in, const int* in_sizes, int n_in,
                              void* d_out, int out_size, void* d_ws, size_t ws_size,
                              hipStream_t stream) {
    const float* x   = (const float*)d_in[0];
    const float* Wqk = (const float*)d_in[1];
    const float* bqk = (const float*)d_in[2];
    const float* Wv  = (const float*)d_in[3];
    const float* bv  = (const float*)d_in[4];
    float* out = (float*)d_out;

    char* ws = (char*)d_ws;
    const size_t SZ_XB = (size_t)MROWS*KDIM*2;    // 8 MB
    const size_t SZ_WT = (size_t)NTOT*KDIM*2;     // 6 MB
    const size_t SZ_F  = (size_t)MROWS*1024*2;    // 8 MB per frag buffer
    __bf16* xb = (__bf16*)(ws);
    __bf16* Wt = (__bf16*)(ws + SZ_XB);
    __bf16* qF = (__bf16*)(ws + SZ_XB + SZ_WT);
    __bf16* kF = (__bf16*)(ws + SZ_XB + SZ_WT + SZ_F);
    __bf16* vF = (__bf16*)(ws + SZ_XB + SZ_WT + 2*SZ_F);

    prep_kernel    <<<2048 + 768, 256, 0, stream>>>(x, Wqk, Wv, xb, Wt);
    gemm_qkv_kernel<<<dim3(NTOT/BN, MROWS/BM), 256, 0, stream>>>(xb, Wt, bqk, bv, qF, kF, vF);
    attn_kernel    <<<dim3(32, 16), 512, 0, stream>>>(qF, kF, vF, out);
}